// Round 8
// baseline (356.333 us; speedup 1.0000x reference)
//
#include <hip/hip_runtime.h>
#include <hip/hip_bf16.h>

// ============================================================================
// HybridModel round 16: l2 LDS squeeze -> 3 blocks/CU (the l3-r14 occupancy).
//  - r15 post-mortem: monolithic l2 fixed barriers/VALU but dur unchanged;
//    l3's r14 win had 3 blocks/CU, l2 is 363 B over the 3-block line.
//  - lin loses its halo COLUMNS ([10][114] -> [10][112], -1096 B); the only
//    two out-of-range A-reads (col -1 at f=0/wi=0/kx=0; col 112 at
//    f=6/wi=15/kx=2) read a 16 B zero-slot via address select.
//  - LDS: 53760 lin + 32 zslot + 256 lstat = 54048 B -> 3 blocks/CU.
//    __launch_bounds__(256,3).
//  - l1 / l3 (r14) / heads unchanged (attribution).
// ============================================================================

typedef _Float16 f16;
typedef _Float16 f16x2 __attribute__((ext_vector_type(2)));
typedef _Float16 f16x4 __attribute__((ext_vector_type(4)));
typedef _Float16 f16x8 __attribute__((ext_vector_type(8)));
typedef float f32x4 __attribute__((ext_vector_type(4)));
typedef float f32x16 __attribute__((ext_vector_type(16)));

#define DEV static __device__ __forceinline__

DEV float wave_sum(float v) {
#pragma unroll
  for (int off = 32; off > 0; off >>= 1) v += __shfl_xor(v, off, 64);
  return v;
}

// ---------------------------------------------------------------------------
// Weight repack: Bt2[32][168] (k = tap*16+ic, pad 144..167 = 0),
//                Bt3[64][296] (k = tap*32+ic, pad 288..295 = 0), f16.
// ---------------------------------------------------------------------------
__global__ __launch_bounds__(256) void repack(const float* __restrict__ w2,
                                              const float* __restrict__ w3,
                                              f16* __restrict__ Bt2,
                                              f16* __restrict__ Bt3) {
  int t = blockIdx.x * 256 + threadIdx.x;
  int T = gridDim.x * 256;
  for (int i = t; i < 32 * 168; i += T) {
    int oc = i / 168, kk = i - oc * 168;
    float v = 0.f;
    if (kk < 144) {
      int tap = kk >> 4, ic = kk & 15;
      v = w2[(oc * 16 + ic) * 9 + tap];
    }
    Bt2[i] = (f16)v;
  }
  for (int i = t; i < 64 * 296; i += T) {
    int oc = i / 296, kk = i - oc * 296;
    float v = 0.f;
    if (kk < 288) {
      int tap = kk / 32, ic = kk & 31;
      v = w3[(oc * 32 + ic) * 9 + tap];
    }
    Bt3[i] = (f16)v;
  }
}

// ---------------------------------------------------------------------------
// Finalize: banks[64][2][C] -> scsh[2][C]  (scale, shift). 64 thr = 1 wave.
// ---------------------------------------------------------------------------
__global__ __launch_bounds__(64) void finalize(const float* __restrict__ banks,
                                               const float* __restrict__ g,
                                               const float* __restrict__ b,
                                               float* __restrict__ scsh, int C,
                                               float inv_n) {
  int c = blockIdx.x, bk = threadIdx.x;
  float s = banks[bk * 2 * C + c];
  float qq = banks[bk * 2 * C + C + c];
  s = wave_sum(s);
  qq = wave_sum(qq);
  if (bk == 0) {
    float mean = s * inv_n;
    float var = qq * inv_n - mean * mean;
    float sc = g[c] * rsqrtf(var + 1e-5f);
    scsh[c] = sc;
    scsh[C + c] = b[c] - mean * sc;
  }
}

// ---------------------------------------------------------------------------
// L1 via 32x32x16 MFMA (dual-output-row). Unchanged from round 6.
// ---------------------------------------------------------------------------
__global__ __launch_bounds__(256) void l1_mfma32(const float* __restrict__ x,
                                                 const float* __restrict__ w1,
                                                 float* __restrict__ banks,
                                                 f16* __restrict__ h1raw) {
  __shared__ f16 xA[18 * 240];
  __shared__ f16 xB[18 * 240];
  __shared__ f16 lrow[4 * 3616];  // per wave: [2 s][1808]
  __shared__ float lstat[32];
  int bid = blockIdx.x;
  int n = bid / 14, band = bid - n * 14;
  int y0 = band * 16;
  int t = threadIdx.x;
  if (t < 32) lstat[t] = 0.f;
  for (int i = t; i < 1008; i += 256) {
    int r = i / 56, k = i - r * 56;
    int y = y0 - 1 + r;
    float4 v = make_float4(0.f, 0.f, 0.f, 0.f);
    if ((unsigned)y < 224u)
      v = *(const float4*)(x + ((size_t)(n * 224 + y)) * 224 + k * 4);
    f16 h0 = (f16)v.x, h1 = (f16)v.y, h2 = (f16)v.z, h3 = (f16)v.w;
    f16* pa = xA + r * 240 + 4 * k + 1;
    pa[0] = h0; pa[1] = h1; pa[2] = h2; pa[3] = h3;
    f16x4 pk = {h0, h1, h2, h3};
    *(f16x4*)(xB + r * 240 + 4 * k) = pk;
  }
  if (t < 18) {
    xA[t * 240 + 0] = (f16)0.f;
    xA[t * 240 + 225] = (f16)0.f;
    xA[t * 240 + 226] = (f16)0.f;
    xB[t * 240 + 224] = (f16)0.f;
    xB[t * 240 + 225] = (f16)0.f;
  }
  __syncthreads();

  int wave = t >> 6, lane = t & 63;
  int g = lane >> 5, m32 = lane & 31;
  int oc = m32 & 15, s = m32 >> 4;

  f16x8 b;
#pragma unroll
  for (int j = 0; j < 8; j++) {
    int ky = 2 * g + (j >> 2), kx = j & 3;
    int kys = ky - s;
    float wv = 0.f;
    if (kx < 3 && kys >= 0 && kys < 3) wv = w1[oc * 9 + kys * 3 + kx];
    b[j] = (f16)wv;
  }

  const f16* abase = (m32 & 1) ? (xB + (m32 - 1)) : (xA + m32);
  f16* myrow = lrow + wave * 3616;
  f16* mrow = myrow + s * 1808;
  f32x16 zero16;
#pragma unroll
  for (int r = 0; r < 16; r++) zero16[r] = 0.f;
  const int bp[8] = {0, 1, 4, 5, 8, 9, 12, 13};
  float ssum = 0.f, ssq = 0.f;

  for (int rp = wave; rp < 8; rp += 4) {
    int r0 = 2 * rp + 2 * g;
    const f16* rbase = abase + r0 * 240;
#pragma unroll
    for (int xt = 0; xt < 7; xt++) {
      const f16* p0 = rbase + xt * 32;
      f16x2 v0 = *(const f16x2*)(p0);
      f16x2 v1 = *(const f16x2*)(p0 + 2);
      f16x2 v2 = *(const f16x2*)(p0 + 240);
      f16x2 v3 = *(const f16x2*)(p0 + 242);
      f16x8 a = {v0[0], v0[1], v1[0], v1[1], v2[0], v2[1], v3[0], v3[1]};
      f32x16 acc = __builtin_amdgcn_mfma_f32_32x32x16_f16(a, b, zero16, 0, 0, 0);
#pragma unroll
      for (int r = 0; r < 16; r++) {
        float v = acc[r];
        ssum += v;
        ssq += v * v;
      }
#pragma unroll
      for (int i = 0; i < 8; i++) {
        float pm = fmaxf(acc[2 * i], acc[2 * i + 1]);
        int pxp = xt * 16 + bp[i] + 2 * g;
        mrow[pxp * 16 + oc] = (f16)pm;
      }
    }
    int ph = band * 8 + rp;
    f16* gdst = h1raw + ((size_t)(n * 112) + ph) * 112 * 16;
    for (int i = lane; i < 224; i += 64) {
      f16x8 va = *(const f16x8*)(myrow + i * 8);
      f16x8 vb = *(const f16x8*)(myrow + 1808 + i * 8);
#pragma unroll
      for (int k = 0; k < 8; k++) va[k] = (va[k] > vb[k]) ? va[k] : vb[k];
      *(f16x8*)(gdst + i * 8) = va;
    }
  }
  ssum += __shfl_xor(ssum, 16, 64);
  ssum += __shfl_xor(ssum, 32, 64);
  ssq += __shfl_xor(ssq, 16, 64);
  ssq += __shfl_xor(ssq, 32, 64);
  if (lane < 16) {
    atomicAdd(&lstat[oc], ssum);
    atomicAdd(&lstat[16 + oc], ssq);
  }
  __syncthreads();
  if (t < 32) atomicAdd(&banks[(bid & 63) * 32 + t], lstat[t]);
}

// ---------------------------------------------------------------------------
// L2 GEMM round 16: monolithic 8-row superband, halo-column-free lin.
// LDS: lin [10][112] pos x 24 f16 = 53760 B + zslot 32 B + lstat 256 B
//    = 54048 B -> 3 blocks/CU. Boundary A-reads (col -1 / col 112) go to
// the zero slot via address select (only f=0 and f=6 can be out of range).
// ---------------------------------------------------------------------------
__global__ __launch_bounds__(256, 3) void l2_gemm(
    const f16* __restrict__ h1, const f16* __restrict__ Btg,
    const float* __restrict__ scsh1, f16* __restrict__ p2,
    float* __restrict__ banks) {
  extern __shared__ char smem[];
  f16* lin = (f16*)smem;                  // [10][112] pos x 24 f16 = 53760 B
  f16* zslot = (f16*)(smem + 53760);      // 32 B (16 used)
  float* lstat = (float*)(smem + 53792);  // [4][16] = 256 B
  int bid = blockIdx.x;
  int n = bid / 14, sb = bid - n * 14;  // img rows sb*8 .. sb*8+7
  int t = threadIdx.x;
  int wave = t >> 6, lane = t & 63, q = lane >> 4, wi = lane & 15;
  const int icq = (q & 1) * 8;

  // B fragments (Bt2 = 10.75 KB, L2-resident).
  f16x8 breg0[5], breg1[5];
#pragma unroll
  for (int j = 0; j < 5; j++) {
    breg0[j] = *(const f16x8*)(Btg + wi * 168 + j * 32 + q * 8);
    breg1[j] = *(const f16x8*)(Btg + (16 + wi) * 168 + j * 32 + q * 8);
  }

  if (t < 64) lstat[t] = 0.f;
  if (t == 0) {
    f16x8 z = {0, 0, 0, 0, 0, 0, 0, 0};
    *(f16x8*)zslot = z;
  }
  // Stage 10 rows (row halo incl), BN1+relu, into lin. 10*224 = 2240 items.
#pragma unroll
  for (int k = 0; k < 9; k++) {
    int i = t + k * 256;
    if (i < 2240) {
      int r = i / 224, c = i - r * 224;  // c: f16x8 unit (pos c>>1, half c&1)
      int y = sb * 8 + r - 1;
      f16x8 o = {0, 0, 0, 0, 0, 0, 0, 0};
      if ((unsigned)y < 112u) {
        f16x8 xv =
            *(const f16x8*)(h1 + ((size_t)(n * 112 + y)) * 112 * 16 + c * 8);
        int ch0 = (c & 1) * 8;
#pragma unroll
        for (int e = 0; e < 8; e++) {
          float f = (float)xv[e] * scsh1[ch0 + e] + scsh1[16 + ch0 + e];
          o[e] = (f16)fmaxf(f, 0.f);
        }
      }
      *(f16x8*)(lin + (r * 112 + (c >> 1)) * 24 + (c & 1) * 8) = o;
    }
  }
  __syncthreads();

  // MFMA: wave owns output rows ro = 2*wave, 2*wave+1 (lin row = ro + ky).
  f32x4 acc[2][7][2];
#pragma unroll
  for (int rr = 0; rr < 2; rr++)
#pragma unroll
    for (int f = 0; f < 7; f++)
#pragma unroll
      for (int nf = 0; nf < 2; nf++)
#pragma unroll
        for (int r = 0; r < 4; r++) acc[rr][f][nf][r] = 0.f;

#pragma unroll
  for (int j = 0; j < 5; j++) {
    const int tA = 2 * j, tB = 2 * j + 1;
    const int kyA = tA / 3, kxA = tA % 3;
    const int kyB = (tB < 9) ? tB / 3 : 0, kxB = (tB < 9) ? tB % 3 : 0;
    bool hiq = (q >= 2);
    int ky = hiq ? kyB : kyA;
    int kx = hiq ? kxB : kxA;
    f16x8 b0 = breg0[j];
    f16x8 b1 = breg1[j];
    int c0 = wi + kx - 1;  // image col for f=0; range [-1, 16]
#pragma unroll
    for (int rr = 0; rr < 2; rr++) {
      int ro = 2 * wave + rr;
      const f16* rowbase = lin + (ro + ky) * 112 * 24 + icq;
      // j==4, hiq: B fragment is Bt2's zero pad (cols 144..159) -> exact 0.
#pragma unroll
      for (int f = 0; f < 7; f++) {
        int col = c0 + f * 16;
        // Only f=0 (col=-1) and f=6 (col=112) can be out of range.
        const f16* ap =
            ((unsigned)col < 112u) ? (rowbase + col * 24) : (const f16*)zslot;
        f16x8 a = *(const f16x8*)ap;
        acc[rr][f][0] =
            __builtin_amdgcn_mfma_f32_16x16x32_f16(a, b0, acc[rr][f][0], 0, 0, 0);
        acc[rr][f][1] =
            __builtin_amdgcn_mfma_f32_16x16x32_f16(a, b1, acc[rr][f][1], 0, 0, 0);
      }
    }
  }

  // Stats (raw conv, pre-pool) over both rows.
  float tS0 = 0.f, tQ0 = 0.f, tS1 = 0.f, tQ1 = 0.f;
#pragma unroll
  for (int rr = 0; rr < 2; rr++)
#pragma unroll
    for (int f = 0; f < 7; f++)
#pragma unroll
      for (int r = 0; r < 4; r++) {
        float v0 = acc[rr][f][0][r], v1 = acc[rr][f][1][r];
        tS0 += v0; tQ0 += v0 * v0;
        tS1 += v1; tQ1 += v1 * v1;
      }

  // 2x2 pool fully in-register (col pairs within acc regs, row pair = rr).
  {
    int ph = sb * 4 + wave;
    size_t ob = (((size_t)n * 56 + ph) * 56) * 32;
#pragma unroll
    for (int f = 0; f < 7; f++)
#pragma unroll
      for (int nf = 0; nf < 2; nf++) {
        int ch = nf * 16 + wi;
        int pc0 = f * 8 + q * 2;
        float a0 = fmaxf(acc[0][f][nf][0], acc[0][f][nf][1]);
        float a1 = fmaxf(acc[0][f][nf][2], acc[0][f][nf][3]);
        float b0m = fmaxf(acc[1][f][nf][0], acc[1][f][nf][1]);
        float b1m = fmaxf(acc[1][f][nf][2], acc[1][f][nf][3]);
        p2[ob + (size_t)pc0 * 32 + ch] = (f16)fmaxf(a0, b0m);
        p2[ob + (size_t)(pc0 + 1) * 32 + ch] = (f16)fmaxf(a1, b1m);
      }
  }

  // Flush stats.
  tS0 += __shfl_xor(tS0, 16, 64); tS0 += __shfl_xor(tS0, 32, 64);
  tQ0 += __shfl_xor(tQ0, 16, 64); tQ0 += __shfl_xor(tQ0, 32, 64);
  tS1 += __shfl_xor(tS1, 16, 64); tS1 += __shfl_xor(tS1, 32, 64);
  tQ1 += __shfl_xor(tQ1, 16, 64); tQ1 += __shfl_xor(tQ1, 32, 64);
  if (q == 0) {
    atomicAdd(&lstat[wi], tS0);
    atomicAdd(&lstat[16 + wi], tS1);
    atomicAdd(&lstat[32 + wi], tQ0);
    atomicAdd(&lstat[48 + wi], tQ1);
  }
  __syncthreads();
  if (t < 64) {
    int i = t >> 5, c = t & 31;
    atomicAdd(&banks[(bid & 63) * 64 + i * 32 + c], lstat[i * 32 + c]);
  }
}

// ---------------------------------------------------------------------------
// L3 GEMM (r14, validated): one block = (n, 8-row superband). Each wave
// computes 112 positions x ALL 64 oc (4 B-frags per A-read).
// LDS: lin [10][58]x40 f16 = 46400 + lstat 512 = 46912 B; lpool aliases lin.
// ---------------------------------------------------------------------------
__global__ __launch_bounds__(256, 2) void l3_gemm(
    const f16* __restrict__ p2, const f16* __restrict__ Btg,
    const float* __restrict__ scsh2, f16* __restrict__ p3,
    float* __restrict__ banks) {
  extern __shared__ char smem[];
  f16* lin = (f16*)smem;                  // [10][58] pos x 40 f16 = 46400 B
  float* lstat = (float*)(smem + 46400);  // [2][64] = 512 B
  f16* lpool = (f16*)smem;                // aliases lin post-MFMA (28672 B)
  int bx = blockIdx.x;
  int n = bx / 7, sb = bx - n * 7;  // img rows sb*8 .. sb*8+7
  int t = threadIdx.x;
  int wave = t >> 6, lane = t & 63, q = lane >> 4, wi = lane & 15;

  // B fragments: all 64 oc per wave (36 x f16x8; Bt3 is L2-resident).
  f16x8 breg[9][4];
#pragma unroll
  for (int j = 0; j < 9; j++)
#pragma unroll
    for (int h = 0; h < 4; h++)
      breg[j][h] =
          *(const f16x8*)(Btg + (h * 16 + wi) * 296 + j * 32 + q * 8);

  if (t < 128) lstat[t] = 0.f;
  // Stage 10 rows (halo included), BN2+relu, into lin.
#pragma unroll
  for (int k = 0; k < 9; k++) {
    int i = t + k * 256;
    if (i < 2240) {
      int r = i / 224, rem = i - r * 224;
      int c = rem >> 2, cp = rem & 3;
      int y = sb * 8 + r - 1;
      f16x8 o = {0, 0, 0, 0, 0, 0, 0, 0};
      if ((unsigned)y < 56u) {
        f16x8 xv =
            *(const f16x8*)(p2 + (((size_t)(n * 56 + y)) * 56 + c) * 32 +
                            cp * 8);
        int ch0 = cp * 8;
#pragma unroll
        for (int e = 0; e < 8; e++) {
          float f = (float)xv[e] * scsh2[ch0 + e] + scsh2[32 + ch0 + e];
          o[e] = (f16)fmaxf(f, 0.f);
        }
      }
      *(f16x8*)(lin + (r * 58 + 1 + c) * 40 + cp * 8) = o;
    }
  }
  // Zero halo columns (pos 0 and 57), rows 0..9.
  if (t < 80) {
    int r = t / 8, k = t & 7;
    int col = (k < 4) ? 0 : 57, cp = k & 3;
    f16x8 z = {0, 0, 0, 0, 0, 0, 0, 0};
    *(f16x8*)(lin + (r * 58 + col) * 40 + cp * 8) = z;
  }
  __syncthreads();

  int abase[7];
#pragma unroll
  for (int f = 0; f < 7; f++) {
    int pos = wave * 112 + f * 16 + wi;
    int r = pos / 56, w = pos - r * 56;
    abase[f] = (r * 58 + w) * 40 + q * 8;
  }
  f32x4 acc[7][4];
#pragma unroll
  for (int f = 0; f < 7; f++)
#pragma unroll
    for (int h = 0; h < 4; h++)
#pragma unroll
      for (int r = 0; r < 4; r++) acc[f][h][r] = 0.f;

#pragma unroll
  for (int j = 0; j < 9; j++) {
    const int ky = j / 3, kx = j % 3;
#pragma unroll
    for (int f = 0; f < 7; f++) {
      f16x8 a = *(const f16x8*)(lin + abase[f] + (ky * 58 + kx) * 40);
#pragma unroll
      for (int h = 0; h < 4; h++)
        acc[f][h] =
            __builtin_amdgcn_mfma_f32_16x16x32_f16(a, breg[j][h], acc[f][h],
                                                   0, 0, 0);
    }
  }

  // Stats: channel = h*16 + wi; reduce across q via shfl, atomic to lstat.
  float tS[4] = {0.f, 0.f, 0.f, 0.f}, tQ[4] = {0.f, 0.f, 0.f, 0.f};
#pragma unroll
  for (int f = 0; f < 7; f++)
#pragma unroll
    for (int h = 0; h < 4; h++)
#pragma unroll
      for (int r = 0; r < 4; r++) {
        float v = acc[f][h][r];
        tS[h] += v;
        tQ[h] += v * v;
      }
#pragma unroll
  for (int h = 0; h < 4; h++) {
    tS[h] += __shfl_xor(tS[h], 16, 64); tS[h] += __shfl_xor(tS[h], 32, 64);
    tQ[h] += __shfl_xor(tQ[h], 16, 64); tQ[h] += __shfl_xor(tQ[h], 32, 64);
  }
  if (q == 0) {
#pragma unroll
    for (int h = 0; h < 4; h++) {
      atomicAdd(&lstat[h * 16 + wi], tS[h]);
      atomicAdd(&lstat[64 + h * 16 + wi], tQ[h]);
    }
  }
  __syncthreads();  // all lin reads done; lpool may now alias lin

  // Col-pair maxes -> lpool[8][28][64].
#pragma unroll
  for (int f = 0; f < 7; f++) {
    int pos = wave * 112 + f * 16 + q * 4;  // multiple of 4
    int r0 = pos / 56, w0 = pos - r0 * 56;
#pragma unroll
    for (int h = 0; h < 4; h++) {
      int ch = h * 16 + wi;
      float m0 = fmaxf(acc[f][h][0], acc[f][h][1]);
      float m1 = fmaxf(acc[f][h][2], acc[f][h][3]);
      lpool[(r0 * 28 + (w0 >> 1)) * 64 + ch] = (f16)m0;
      lpool[(r0 * 28 + (w0 >> 1) + 1) * 64 + ch] = (f16)m1;
    }
  }
  __syncthreads();

  // Row-pair combine + p3 store (4 pooled rows x 28 x 64 = 7168).
  for (int i = t; i < 7168; i += 256) {
    int ch = i & 63, rest = i >> 6;
    int pc = rest % 28, pr = rest / 28;  // pr 0..3
    float v = fmaxf((float)lpool[((2 * pr) * 28 + pc) * 64 + ch],
                    (float)lpool[((2 * pr + 1) * 28 + pc) * 64 + ch]);
    int gpr = sb * 4 + pr;
    p3[(((size_t)n * 28 + gpr) * 28 + pc) * 64 + ch] = (f16)v;
  }
  if (t < 128) {
    atomicAdd(&banks[(bx & 63) * 128 + t], lstat[t]);
  }
}

// ---------------------------------------------------------------------------
// head_pool: BN3+relu+avgpool(p3) coalesced + fc1 -> feat[n][8] (first 5).
// ---------------------------------------------------------------------------
__global__ __launch_bounds__(256) void head_pool(
    const f16* __restrict__ p3, const float* __restrict__ scsh3,
    const float* __restrict__ fc1w, const float* __restrict__ fc1b,
    float* __restrict__ featg) {
  int n = blockIdx.x, t = threadIdx.x;
  __shared__ float red[64 * 33];
  __shared__ float meanc[64];
  int oct = t & 7, strip = t >> 3;
  float sc[8], sh[8];
#pragma unroll
  for (int k = 0; k < 8; k++) {
    sc[k] = scsh3[oct * 8 + k];
    sh[k] = scsh3[64 + oct * 8 + k];
  }
  float acc[8];
#pragma unroll
  for (int k = 0; k < 8; k++) acc[k] = 0.f;
  const f16* base = p3 + (size_t)n * 50176 + oct * 8;
  for (int px = strip; px < 784; px += 32) {
    f16x8 v = *(const f16x8*)(base + (size_t)px * 64);
#pragma unroll
    for (int k = 0; k < 8; k++)
      acc[k] += fmaxf((float)v[k] * sc[k] + sh[k], 0.f);
  }
#pragma unroll
  for (int k = 0; k < 8; k++) red[(oct * 8 + k) * 33 + strip] = acc[k];
  __syncthreads();
  if (t < 64) {
    float s = 0.f;
    for (int j = 0; j < 32; j++) s += red[t * 33 + j];
    meanc[t] = s * (1.f / 784.f);
  }
  __syncthreads();
  if (t < 5) {
    float a = fc1b[t];
    for (int i = 0; i < 64; i++) a += meanc[i] * fc1w[i * 5 + t];
    featg[n * 8 + t] = a;
  }
}

// ---------------------------------------------------------------------------
// Quantum gates in registers. Wire w <-> bit (4-w). (verified rounds 1-7)
// ---------------------------------------------------------------------------
template <int W>
DEV void g_rx(float (&sr)[32], float (&si)[32], float c, float s) {
  constexpr int m = 1 << (4 - W);
#pragma unroll
  for (int i0 = 0; i0 < 32; i0++)
    if (!(i0 & m)) {
      int i1 = i0 | m;
      float a0r = sr[i0], a0i = si[i0], a1r = sr[i1], a1i = si[i1];
      sr[i0] = c * a0r + s * a1i;
      si[i0] = c * a0i - s * a1r;
      sr[i1] = s * a0i + c * a1r;
      si[i1] = -s * a0r + c * a1i;
    }
}

template <int W>
DEV void g_ry(float (&sr)[32], float (&si)[32], float c, float s) {
  constexpr int m = 1 << (4 - W);
#pragma unroll
  for (int i0 = 0; i0 < 32; i0++)
    if (!(i0 & m)) {
      int i1 = i0 | m;
      float a0r = sr[i0], a0i = si[i0], a1r = sr[i1], a1i = si[i1];
      sr[i0] = c * a0r - s * a1r;
      si[i0] = c * a0i - s * a1i;
      sr[i1] = s * a0r + c * a1r;
      si[i1] = s * a0i + c * a1i;
    }
}

template <int W>
DEV void g_rz(float (&sr)[32], float (&si)[32], float c, float s) {
  constexpr int m = 1 << (4 - W);
#pragma unroll
  for (int i0 = 0; i0 < 32; i0++)
    if (!(i0 & m)) {
      int i1 = i0 | m;
      float a0r = sr[i0], a0i = si[i0], a1r = sr[i1], a1i = si[i1];
      sr[i0] = c * a0r + s * a0i;
      si[i0] = c * a0i - s * a0r;
      sr[i1] = c * a1r - s * a1i;
      si[i1] = c * a1i + s * a1r;
    }
}

template <int C, int T>
DEV void g_cnot(float (&sr)[32], float (&si)[32]) {
  constexpr int mc = 1 << (4 - C), mt = 1 << (4 - T);
#pragma unroll
  for (int i0 = 0; i0 < 32; i0++)
    if ((i0 & mc) && !(i0 & mt)) {
      int i1 = i0 | mt;
      float tr = sr[i0]; sr[i0] = sr[i1]; sr[i1] = tr;
      float ti = si[i0]; si[i0] = si[i1]; si[i1] = ti;
    }
}

// ---------------------------------------------------------------------------
// head_q: one thread per sample. LN -> quantum -> fc2 -> relu -> fc3 ->
// log_softmax.
// ---------------------------------------------------------------------------
__global__ __launch_bounds__(64) void head_q(
    const float* __restrict__ featg, const float* __restrict__ lng,
    const float* __restrict__ lnb, const float* __restrict__ qp,
    const float* __restrict__ fc2w, const float* __restrict__ fc2b,
    const float* __restrict__ fc3w, const float* __restrict__ fc3b,
    float* __restrict__ out) {
  int n = blockIdx.x * 64 + threadIdx.x;
  float f[5];
#pragma unroll
  for (int i = 0; i < 5; i++) f[i] = featg[n * 8 + i];
  float mu = (f[0] + f[1] + f[2] + f[3] + f[4]) * 0.2f;
  float var = 0.f;
#pragma unroll
  for (int i = 0; i < 5; i++) { float d = f[i] - mu; var += d * d; }
  var *= 0.2f;
  float inv = rsqrtf(var + 1e-5f);
#pragma unroll
  for (int i = 0; i < 5; i++) f[i] = lng[i] * (f[i] - mu) * inv + lnb[i];

  float cx[5], sx[5];
#pragma unroll
  for (int i = 0; i < 5; i++) {
    cx[i] = cosf(0.5f * f[i]);
    sx[i] = sinf(0.5f * f[i]);
  }
  float sr[32], si[32];
#pragma unroll
  for (int i = 0; i < 32; i++) { sr[i] = 0.f; si[i] = 0.f; }
  sr[0] = 1.f;

  for (int l = 0; l < 3; l++) {
    g_rx<0>(sr, si, cx[0], sx[0]);
    g_rx<1>(sr, si, cx[1], sx[1]);
    g_rx<2>(sr, si, cx[2], sx[2]);
    g_rx<3>(sr, si, cx[3], sx[3]);
    g_rx<4>(sr, si, cx[4], sx[4]);
#define WIRE_YZ(I)                                             \
  {                                                            \
    float ty = qp[l * 10 + I];                                 \
    g_ry<I>(sr, si, cosf(0.5f * ty), sinf(0.5f * ty));         \
    float tz = qp[l * 10 + I + 5];                             \
    g_rz<I>(sr, si, cosf(0.5f * tz), sinf(0.5f * tz));         \
  }
    WIRE_YZ(0) WIRE_YZ(1) WIRE_YZ(2) WIRE_YZ(3) WIRE_YZ(4)
#undef WIRE_YZ
    g_cnot<0, 1>(sr, si);
    g_cnot<1, 2>(sr, si);
    g_cnot<2, 3>(sr, si);
    g_cnot<3, 4>(sr, si);
    g_cnot<4, 0>(sr, si);
  }
  float qv = 0.f;
#pragma unroll
  for (int idx = 0; idx < 32; idx++) {
    float p = sr[idx] * sr[idx] + si[idx] * si[idx];
    qv += (__popc(idx & 0x1C) & 1) ? -p : p;
  }
  float l0 = fc3b[0], l1 = fc3b[1];
  for (int j = 0; j < 32; j++) {
    float hv = fmaxf(qv * fc2w[j] + fc2b[j], 0.f);
    l0 += hv * fc3w[j * 2];
    l1 += hv * fc3w[j * 2 + 1];
  }
  float mx = fmaxf(l0, l1);
  float lse = mx + logf(expf(l0 - mx) + expf(l1 - mx));
  out[n * 2 + 0] = l0 - lse;
  out[n * 2 + 1] = l1 - lse;
}

// ---------------------------------------------------------------------------
extern "C" void kernel_launch(void* const* d_in, const int* in_sizes, int n_in,
                              void* d_out, int out_size, void* d_ws,
                              size_t ws_size, hipStream_t stream) {
  const float* x    = (const float*)d_in[0];
  const float* w1   = (const float*)d_in[1];
  const float* bn1g = (const float*)d_in[3];
  const float* bn1b = (const float*)d_in[4];
  const float* w2   = (const float*)d_in[5];
  const float* bn2g = (const float*)d_in[7];
  const float* bn2b = (const float*)d_in[8];
  const float* w3   = (const float*)d_in[9];
  const float* bn3g = (const float*)d_in[11];
  const float* bn3b = (const float*)d_in[12];
  const float* fc1w = (const float*)d_in[13];
  const float* fc1b = (const float*)d_in[14];
  const float* lng  = (const float*)d_in[15];
  const float* lnb  = (const float*)d_in[16];
  const float* qp   = (const float*)d_in[17];
  const float* fc2w = (const float*)d_in[18];
  const float* fc2b = (const float*)d_in[19];
  const float* fc3w = (const float*)d_in[20];
  const float* fc3b = (const float*)d_in[21];
  float* out = (float*)d_out;

  char* ws = (char*)d_ws;
  float* banks1 = (float*)ws;                 // [64][2][16]  8192 B
  float* banks2 = (float*)(ws + 8192);        // [64][2][32] 16384 B (reused as featg)
  float* banks3 = (float*)(ws + 24576);       // [64][2][64] 32768 B
  float* scsh1 = (float*)(ws + 57344);        // [2][16]
  float* scsh2 = (float*)(ws + 57472);        // [2][32]
  float* scsh3 = (float*)(ws + 57728);        // [2][64]
  f16* Bt2 = (f16*)(ws + 58240);              // 32*168 f16 = 10752 B
  f16* Bt3 = (f16*)(ws + 68992);              // 64*296 f16 = 37888 B
  f16* h1 = (f16*)(ws + 106880);              // 51,380,224 el (raw pooled)
  f16* p2 = (f16*)(ws + 106880 + 102760448ULL);
  f16* p3 = (f16*)(ws + 106880 + 102760448ULL + 51380224ULL);
  float* featg = banks2;                      // free by head time

  hipMemsetAsync(ws, 0, 57344, stream);
  repack<<<16, 256, 0, stream>>>(w2, w3, Bt2, Bt3);
  l1_mfma32<<<3584, 256, 0, stream>>>(x, w1, banks1, h1);
  finalize<<<16, 64, 0, stream>>>(banks1, bn1g, bn1b, scsh1, 16,
                                  1.f / 12845056.f);
  l2_gemm<<<3584, 256, 54048, stream>>>(h1, Bt2, scsh1, p2, banks2);
  finalize<<<32, 64, 0, stream>>>(banks2, bn2g, bn2b, scsh2, 32,
                                  1.f / 3211264.f);
  l3_gemm<<<1792, 256, 46912, stream>>>(p2, Bt3, scsh2, p3, banks3);
  finalize<<<64, 64, 0, stream>>>(banks3, bn3g, bn3b, scsh3, 64,
                                  1.f / 802816.f);
  head_pool<<<256, 256, 0, stream>>>(p3, scsh3, fc1w, fc1b, featg);
  head_q<<<4, 64, 0, stream>>>(featg, lng, lnb, qp, fc2w, fc2b, fc3w, fc3b,
                               out);
}

// Round 9
// 354.096 us; speedup vs baseline: 1.0063x; 1.0063x over previous
//
#include <hip/hip_runtime.h>
#include <hip/hip_bf16.h>

// ============================================================================
// HybridModel round 17: r16 LDS-squeeze retry with launch_bounds(256,2).
//  - r16 post-mortem: (256,3) forced VGPR=84 < 112 acc floats -> scratch
//    spills (WRITE_SIZE 51->76.5 MB), l2 regressed to 82 us. The squeeze
//    itself is fine: 54048 B < 54613 B = 160K/3, so HW fits 3 blocks/CU
//    provided VGPR <= 170 — which the natural allocation (~110-130) satisfies.
//  - Only change vs r16: l2 __launch_bounds__(256, 2). Everything else same.
//  - (40 ms l3 dispatch in r16 profile = rocprof replay artifact; wall time
//    356 us total. l3 kept at r14 form.)
// ============================================================================

typedef _Float16 f16;
typedef _Float16 f16x2 __attribute__((ext_vector_type(2)));
typedef _Float16 f16x4 __attribute__((ext_vector_type(4)));
typedef _Float16 f16x8 __attribute__((ext_vector_type(8)));
typedef float f32x4 __attribute__((ext_vector_type(4)));
typedef float f32x16 __attribute__((ext_vector_type(16)));

#define DEV static __device__ __forceinline__

DEV float wave_sum(float v) {
#pragma unroll
  for (int off = 32; off > 0; off >>= 1) v += __shfl_xor(v, off, 64);
  return v;
}

// ---------------------------------------------------------------------------
// Weight repack: Bt2[32][168] (k = tap*16+ic, pad 144..167 = 0),
//                Bt3[64][296] (k = tap*32+ic, pad 288..295 = 0), f16.
// ---------------------------------------------------------------------------
__global__ __launch_bounds__(256) void repack(const float* __restrict__ w2,
                                              const float* __restrict__ w3,
                                              f16* __restrict__ Bt2,
                                              f16* __restrict__ Bt3) {
  int t = blockIdx.x * 256 + threadIdx.x;
  int T = gridDim.x * 256;
  for (int i = t; i < 32 * 168; i += T) {
    int oc = i / 168, kk = i - oc * 168;
    float v = 0.f;
    if (kk < 144) {
      int tap = kk >> 4, ic = kk & 15;
      v = w2[(oc * 16 + ic) * 9 + tap];
    }
    Bt2[i] = (f16)v;
  }
  for (int i = t; i < 64 * 296; i += T) {
    int oc = i / 296, kk = i - oc * 296;
    float v = 0.f;
    if (kk < 288) {
      int tap = kk / 32, ic = kk & 31;
      v = w3[(oc * 32 + ic) * 9 + tap];
    }
    Bt3[i] = (f16)v;
  }
}

// ---------------------------------------------------------------------------
// Finalize: banks[64][2][C] -> scsh[2][C]  (scale, shift). 64 thr = 1 wave.
// ---------------------------------------------------------------------------
__global__ __launch_bounds__(64) void finalize(const float* __restrict__ banks,
                                               const float* __restrict__ g,
                                               const float* __restrict__ b,
                                               float* __restrict__ scsh, int C,
                                               float inv_n) {
  int c = blockIdx.x, bk = threadIdx.x;
  float s = banks[bk * 2 * C + c];
  float qq = banks[bk * 2 * C + C + c];
  s = wave_sum(s);
  qq = wave_sum(qq);
  if (bk == 0) {
    float mean = s * inv_n;
    float var = qq * inv_n - mean * mean;
    float sc = g[c] * rsqrtf(var + 1e-5f);
    scsh[c] = sc;
    scsh[C + c] = b[c] - mean * sc;
  }
}

// ---------------------------------------------------------------------------
// L1 via 32x32x16 MFMA (dual-output-row). Unchanged from round 6.
// ---------------------------------------------------------------------------
__global__ __launch_bounds__(256) void l1_mfma32(const float* __restrict__ x,
                                                 const float* __restrict__ w1,
                                                 float* __restrict__ banks,
                                                 f16* __restrict__ h1raw) {
  __shared__ f16 xA[18 * 240];
  __shared__ f16 xB[18 * 240];
  __shared__ f16 lrow[4 * 3616];  // per wave: [2 s][1808]
  __shared__ float lstat[32];
  int bid = blockIdx.x;
  int n = bid / 14, band = bid - n * 14;
  int y0 = band * 16;
  int t = threadIdx.x;
  if (t < 32) lstat[t] = 0.f;
  for (int i = t; i < 1008; i += 256) {
    int r = i / 56, k = i - r * 56;
    int y = y0 - 1 + r;
    float4 v = make_float4(0.f, 0.f, 0.f, 0.f);
    if ((unsigned)y < 224u)
      v = *(const float4*)(x + ((size_t)(n * 224 + y)) * 224 + k * 4);
    f16 h0 = (f16)v.x, h1 = (f16)v.y, h2 = (f16)v.z, h3 = (f16)v.w;
    f16* pa = xA + r * 240 + 4 * k + 1;
    pa[0] = h0; pa[1] = h1; pa[2] = h2; pa[3] = h3;
    f16x4 pk = {h0, h1, h2, h3};
    *(f16x4*)(xB + r * 240 + 4 * k) = pk;
  }
  if (t < 18) {
    xA[t * 240 + 0] = (f16)0.f;
    xA[t * 240 + 225] = (f16)0.f;
    xA[t * 240 + 226] = (f16)0.f;
    xB[t * 240 + 224] = (f16)0.f;
    xB[t * 240 + 225] = (f16)0.f;
  }
  __syncthreads();

  int wave = t >> 6, lane = t & 63;
  int g = lane >> 5, m32 = lane & 31;
  int oc = m32 & 15, s = m32 >> 4;

  f16x8 b;
#pragma unroll
  for (int j = 0; j < 8; j++) {
    int ky = 2 * g + (j >> 2), kx = j & 3;
    int kys = ky - s;
    float wv = 0.f;
    if (kx < 3 && kys >= 0 && kys < 3) wv = w1[oc * 9 + kys * 3 + kx];
    b[j] = (f16)wv;
  }

  const f16* abase = (m32 & 1) ? (xB + (m32 - 1)) : (xA + m32);
  f16* myrow = lrow + wave * 3616;
  f16* mrow = myrow + s * 1808;
  f32x16 zero16;
#pragma unroll
  for (int r = 0; r < 16; r++) zero16[r] = 0.f;
  const int bp[8] = {0, 1, 4, 5, 8, 9, 12, 13};
  float ssum = 0.f, ssq = 0.f;

  for (int rp = wave; rp < 8; rp += 4) {
    int r0 = 2 * rp + 2 * g;
    const f16* rbase = abase + r0 * 240;
#pragma unroll
    for (int xt = 0; xt < 7; xt++) {
      const f16* p0 = rbase + xt * 32;
      f16x2 v0 = *(const f16x2*)(p0);
      f16x2 v1 = *(const f16x2*)(p0 + 2);
      f16x2 v2 = *(const f16x2*)(p0 + 240);
      f16x2 v3 = *(const f16x2*)(p0 + 242);
      f16x8 a = {v0[0], v0[1], v1[0], v1[1], v2[0], v2[1], v3[0], v3[1]};
      f32x16 acc = __builtin_amdgcn_mfma_f32_32x32x16_f16(a, b, zero16, 0, 0, 0);
#pragma unroll
      for (int r = 0; r < 16; r++) {
        float v = acc[r];
        ssum += v;
        ssq += v * v;
      }
#pragma unroll
      for (int i = 0; i < 8; i++) {
        float pm = fmaxf(acc[2 * i], acc[2 * i + 1]);
        int pxp = xt * 16 + bp[i] + 2 * g;
        mrow[pxp * 16 + oc] = (f16)pm;
      }
    }
    int ph = band * 8 + rp;
    f16* gdst = h1raw + ((size_t)(n * 112) + ph) * 112 * 16;
    for (int i = lane; i < 224; i += 64) {
      f16x8 va = *(const f16x8*)(myrow + i * 8);
      f16x8 vb = *(const f16x8*)(myrow + 1808 + i * 8);
#pragma unroll
      for (int k = 0; k < 8; k++) va[k] = (va[k] > vb[k]) ? va[k] : vb[k];
      *(f16x8*)(gdst + i * 8) = va;
    }
  }
  ssum += __shfl_xor(ssum, 16, 64);
  ssum += __shfl_xor(ssum, 32, 64);
  ssq += __shfl_xor(ssq, 16, 64);
  ssq += __shfl_xor(ssq, 32, 64);
  if (lane < 16) {
    atomicAdd(&lstat[oc], ssum);
    atomicAdd(&lstat[16 + oc], ssq);
  }
  __syncthreads();
  if (t < 32) atomicAdd(&banks[(bid & 63) * 32 + t], lstat[t]);
}

// ---------------------------------------------------------------------------
// L2 GEMM round 17: monolithic 8-row superband, halo-column-free lin.
// LDS: lin [10][112] pos x 24 f16 = 53760 B + zslot 32 B + lstat 256 B
//    = 54048 B (< 54613 = 160K/3 -> HW fits 3 blocks/CU).
// launch_bounds(256,2): do NOT constrain the allocator (r16's (256,3)
// spilled the 112-float accumulator to scratch).
// ---------------------------------------------------------------------------
__global__ __launch_bounds__(256, 2) void l2_gemm(
    const f16* __restrict__ h1, const f16* __restrict__ Btg,
    const float* __restrict__ scsh1, f16* __restrict__ p2,
    float* __restrict__ banks) {
  extern __shared__ char smem[];
  f16* lin = (f16*)smem;                  // [10][112] pos x 24 f16 = 53760 B
  f16* zslot = (f16*)(smem + 53760);      // 32 B (16 used)
  float* lstat = (float*)(smem + 53792);  // [4][16] = 256 B
  int bid = blockIdx.x;
  int n = bid / 14, sb = bid - n * 14;  // img rows sb*8 .. sb*8+7
  int t = threadIdx.x;
  int wave = t >> 6, lane = t & 63, q = lane >> 4, wi = lane & 15;
  const int icq = (q & 1) * 8;

  // B fragments (Bt2 = 10.75 KB, L2-resident).
  f16x8 breg0[5], breg1[5];
#pragma unroll
  for (int j = 0; j < 5; j++) {
    breg0[j] = *(const f16x8*)(Btg + wi * 168 + j * 32 + q * 8);
    breg1[j] = *(const f16x8*)(Btg + (16 + wi) * 168 + j * 32 + q * 8);
  }

  if (t < 64) lstat[t] = 0.f;
  if (t == 0) {
    f16x8 z = {0, 0, 0, 0, 0, 0, 0, 0};
    *(f16x8*)zslot = z;
  }
  // Stage 10 rows (row halo incl), BN1+relu, into lin. 10*224 = 2240 items.
#pragma unroll
  for (int k = 0; k < 9; k++) {
    int i = t + k * 256;
    if (i < 2240) {
      int r = i / 224, c = i - r * 224;  // c: f16x8 unit (pos c>>1, half c&1)
      int y = sb * 8 + r - 1;
      f16x8 o = {0, 0, 0, 0, 0, 0, 0, 0};
      if ((unsigned)y < 112u) {
        f16x8 xv =
            *(const f16x8*)(h1 + ((size_t)(n * 112 + y)) * 112 * 16 + c * 8);
        int ch0 = (c & 1) * 8;
#pragma unroll
        for (int e = 0; e < 8; e++) {
          float f = (float)xv[e] * scsh1[ch0 + e] + scsh1[16 + ch0 + e];
          o[e] = (f16)fmaxf(f, 0.f);
        }
      }
      *(f16x8*)(lin + (r * 112 + (c >> 1)) * 24 + (c & 1) * 8) = o;
    }
  }
  __syncthreads();

  // MFMA: wave owns output rows ro = 2*wave, 2*wave+1 (lin row = ro + ky).
  f32x4 acc[2][7][2];
#pragma unroll
  for (int rr = 0; rr < 2; rr++)
#pragma unroll
    for (int f = 0; f < 7; f++)
#pragma unroll
      for (int nf = 0; nf < 2; nf++)
#pragma unroll
        for (int r = 0; r < 4; r++) acc[rr][f][nf][r] = 0.f;

#pragma unroll
  for (int j = 0; j < 5; j++) {
    const int tA = 2 * j, tB = 2 * j + 1;
    const int kyA = tA / 3, kxA = tA % 3;
    const int kyB = (tB < 9) ? tB / 3 : 0, kxB = (tB < 9) ? tB % 3 : 0;
    bool hiq = (q >= 2);
    int ky = hiq ? kyB : kyA;
    int kx = hiq ? kxB : kxA;
    f16x8 b0 = breg0[j];
    f16x8 b1 = breg1[j];
    int c0 = wi + kx - 1;  // image col for f=0; range [-1, 16]
#pragma unroll
    for (int rr = 0; rr < 2; rr++) {
      int ro = 2 * wave + rr;
      const f16* rowbase = lin + (ro + ky) * 112 * 24 + icq;
      // j==4, hiq: B fragment is Bt2's zero pad (cols 144..159) -> exact 0.
#pragma unroll
      for (int f = 0; f < 7; f++) {
        int col = c0 + f * 16;
        // Only f=0 (col=-1) and f=6 (col=112) can be out of range.
        const f16* ap =
            ((unsigned)col < 112u) ? (rowbase + col * 24) : (const f16*)zslot;
        f16x8 a = *(const f16x8*)ap;
        acc[rr][f][0] =
            __builtin_amdgcn_mfma_f32_16x16x32_f16(a, b0, acc[rr][f][0], 0, 0, 0);
        acc[rr][f][1] =
            __builtin_amdgcn_mfma_f32_16x16x32_f16(a, b1, acc[rr][f][1], 0, 0, 0);
      }
    }
  }

  // Stats (raw conv, pre-pool) over both rows.
  float tS0 = 0.f, tQ0 = 0.f, tS1 = 0.f, tQ1 = 0.f;
#pragma unroll
  for (int rr = 0; rr < 2; rr++)
#pragma unroll
    for (int f = 0; f < 7; f++)
#pragma unroll
      for (int r = 0; r < 4; r++) {
        float v0 = acc[rr][f][0][r], v1 = acc[rr][f][1][r];
        tS0 += v0; tQ0 += v0 * v0;
        tS1 += v1; tQ1 += v1 * v1;
      }

  // 2x2 pool fully in-register (col pairs within acc regs, row pair = rr).
  {
    int ph = sb * 4 + wave;
    size_t ob = (((size_t)n * 56 + ph) * 56) * 32;
#pragma unroll
    for (int f = 0; f < 7; f++)
#pragma unroll
      for (int nf = 0; nf < 2; nf++) {
        int ch = nf * 16 + wi;
        int pc0 = f * 8 + q * 2;
        float a0 = fmaxf(acc[0][f][nf][0], acc[0][f][nf][1]);
        float a1 = fmaxf(acc[0][f][nf][2], acc[0][f][nf][3]);
        float b0m = fmaxf(acc[1][f][nf][0], acc[1][f][nf][1]);
        float b1m = fmaxf(acc[1][f][nf][2], acc[1][f][nf][3]);
        p2[ob + (size_t)pc0 * 32 + ch] = (f16)fmaxf(a0, b0m);
        p2[ob + (size_t)(pc0 + 1) * 32 + ch] = (f16)fmaxf(a1, b1m);
      }
  }

  // Flush stats.
  tS0 += __shfl_xor(tS0, 16, 64); tS0 += __shfl_xor(tS0, 32, 64);
  tQ0 += __shfl_xor(tQ0, 16, 64); tQ0 += __shfl_xor(tQ0, 32, 64);
  tS1 += __shfl_xor(tS1, 16, 64); tS1 += __shfl_xor(tS1, 32, 64);
  tQ1 += __shfl_xor(tQ1, 16, 64); tQ1 += __shfl_xor(tQ1, 32, 64);
  if (q == 0) {
    atomicAdd(&lstat[wi], tS0);
    atomicAdd(&lstat[16 + wi], tS1);
    atomicAdd(&lstat[32 + wi], tQ0);
    atomicAdd(&lstat[48 + wi], tQ1);
  }
  __syncthreads();
  if (t < 64) {
    int i = t >> 5, c = t & 31;
    atomicAdd(&banks[(bid & 63) * 64 + i * 32 + c], lstat[i * 32 + c]);
  }
}

// ---------------------------------------------------------------------------
// L3 GEMM (r14, validated): one block = (n, 8-row superband). Each wave
// computes 112 positions x ALL 64 oc (4 B-frags per A-read).
// LDS: lin [10][58]x40 f16 = 46400 + lstat 512 = 46912 B; lpool aliases lin.
// ---------------------------------------------------------------------------
__global__ __launch_bounds__(256, 2) void l3_gemm(
    const f16* __restrict__ p2, const f16* __restrict__ Btg,
    const float* __restrict__ scsh2, f16* __restrict__ p3,
    float* __restrict__ banks) {
  extern __shared__ char smem[];
  f16* lin = (f16*)smem;                  // [10][58] pos x 40 f16 = 46400 B
  float* lstat = (float*)(smem + 46400);  // [2][64] = 512 B
  f16* lpool = (f16*)smem;                // aliases lin post-MFMA (28672 B)
  int bx = blockIdx.x;
  int n = bx / 7, sb = bx - n * 7;  // img rows sb*8 .. sb*8+7
  int t = threadIdx.x;
  int wave = t >> 6, lane = t & 63, q = lane >> 4, wi = lane & 15;

  // B fragments: all 64 oc per wave (36 x f16x8; Bt3 is L2-resident).
  f16x8 breg[9][4];
#pragma unroll
  for (int j = 0; j < 9; j++)
#pragma unroll
    for (int h = 0; h < 4; h++)
      breg[j][h] =
          *(const f16x8*)(Btg + (h * 16 + wi) * 296 + j * 32 + q * 8);

  if (t < 128) lstat[t] = 0.f;
  // Stage 10 rows (halo included), BN2+relu, into lin.
#pragma unroll
  for (int k = 0; k < 9; k++) {
    int i = t + k * 256;
    if (i < 2240) {
      int r = i / 224, rem = i - r * 224;
      int c = rem >> 2, cp = rem & 3;
      int y = sb * 8 + r - 1;
      f16x8 o = {0, 0, 0, 0, 0, 0, 0, 0};
      if ((unsigned)y < 56u) {
        f16x8 xv =
            *(const f16x8*)(p2 + (((size_t)(n * 56 + y)) * 56 + c) * 32 +
                            cp * 8);
        int ch0 = cp * 8;
#pragma unroll
        for (int e = 0; e < 8; e++) {
          float f = (float)xv[e] * scsh2[ch0 + e] + scsh2[32 + ch0 + e];
          o[e] = (f16)fmaxf(f, 0.f);
        }
      }
      *(f16x8*)(lin + (r * 58 + 1 + c) * 40 + cp * 8) = o;
    }
  }
  // Zero halo columns (pos 0 and 57), rows 0..9.
  if (t < 80) {
    int r = t / 8, k = t & 7;
    int col = (k < 4) ? 0 : 57, cp = k & 3;
    f16x8 z = {0, 0, 0, 0, 0, 0, 0, 0};
    *(f16x8*)(lin + (r * 58 + col) * 40 + cp * 8) = z;
  }
  __syncthreads();

  int abase[7];
#pragma unroll
  for (int f = 0; f < 7; f++) {
    int pos = wave * 112 + f * 16 + wi;
    int r = pos / 56, w = pos - r * 56;
    abase[f] = (r * 58 + w) * 40 + q * 8;
  }
  f32x4 acc[7][4];
#pragma unroll
  for (int f = 0; f < 7; f++)
#pragma unroll
    for (int h = 0; h < 4; h++)
#pragma unroll
      for (int r = 0; r < 4; r++) acc[f][h][r] = 0.f;

#pragma unroll
  for (int j = 0; j < 9; j++) {
    const int ky = j / 3, kx = j % 3;
#pragma unroll
    for (int f = 0; f < 7; f++) {
      f16x8 a = *(const f16x8*)(lin + abase[f] + (ky * 58 + kx) * 40);
#pragma unroll
      for (int h = 0; h < 4; h++)
        acc[f][h] =
            __builtin_amdgcn_mfma_f32_16x16x32_f16(a, breg[j][h], acc[f][h],
                                                   0, 0, 0);
    }
  }

  // Stats: channel = h*16 + wi; reduce across q via shfl, atomic to lstat.
  float tS[4] = {0.f, 0.f, 0.f, 0.f}, tQ[4] = {0.f, 0.f, 0.f, 0.f};
#pragma unroll
  for (int f = 0; f < 7; f++)
#pragma unroll
    for (int h = 0; h < 4; h++)
#pragma unroll
      for (int r = 0; r < 4; r++) {
        float v = acc[f][h][r];
        tS[h] += v;
        tQ[h] += v * v;
      }
#pragma unroll
  for (int h = 0; h < 4; h++) {
    tS[h] += __shfl_xor(tS[h], 16, 64); tS[h] += __shfl_xor(tS[h], 32, 64);
    tQ[h] += __shfl_xor(tQ[h], 16, 64); tQ[h] += __shfl_xor(tQ[h], 32, 64);
  }
  if (q == 0) {
#pragma unroll
    for (int h = 0; h < 4; h++) {
      atomicAdd(&lstat[h * 16 + wi], tS[h]);
      atomicAdd(&lstat[64 + h * 16 + wi], tQ[h]);
    }
  }
  __syncthreads();  // all lin reads done; lpool may now alias lin

  // Col-pair maxes -> lpool[8][28][64].
#pragma unroll
  for (int f = 0; f < 7; f++) {
    int pos = wave * 112 + f * 16 + q * 4;  // multiple of 4
    int r0 = pos / 56, w0 = pos - r0 * 56;
#pragma unroll
    for (int h = 0; h < 4; h++) {
      int ch = h * 16 + wi;
      float m0 = fmaxf(acc[f][h][0], acc[f][h][1]);
      float m1 = fmaxf(acc[f][h][2], acc[f][h][3]);
      lpool[(r0 * 28 + (w0 >> 1)) * 64 + ch] = (f16)m0;
      lpool[(r0 * 28 + (w0 >> 1) + 1) * 64 + ch] = (f16)m1;
    }
  }
  __syncthreads();

  // Row-pair combine + p3 store (4 pooled rows x 28 x 64 = 7168).
  for (int i = t; i < 7168; i += 256) {
    int ch = i & 63, rest = i >> 6;
    int pc = rest % 28, pr = rest / 28;  // pr 0..3
    float v = fmaxf((float)lpool[((2 * pr) * 28 + pc) * 64 + ch],
                    (float)lpool[((2 * pr + 1) * 28 + pc) * 64 + ch]);
    int gpr = sb * 4 + pr;
    p3[(((size_t)n * 28 + gpr) * 28 + pc) * 64 + ch] = (f16)v;
  }
  if (t < 128) {
    atomicAdd(&banks[(bx & 63) * 128 + t], lstat[t]);
  }
}

// ---------------------------------------------------------------------------
// head_pool: BN3+relu+avgpool(p3) coalesced + fc1 -> feat[n][8] (first 5).
// ---------------------------------------------------------------------------
__global__ __launch_bounds__(256) void head_pool(
    const f16* __restrict__ p3, const float* __restrict__ scsh3,
    const float* __restrict__ fc1w, const float* __restrict__ fc1b,
    float* __restrict__ featg) {
  int n = blockIdx.x, t = threadIdx.x;
  __shared__ float red[64 * 33];
  __shared__ float meanc[64];
  int oct = t & 7, strip = t >> 3;
  float sc[8], sh[8];
#pragma unroll
  for (int k = 0; k < 8; k++) {
    sc[k] = scsh3[oct * 8 + k];
    sh[k] = scsh3[64 + oct * 8 + k];
  }
  float acc[8];
#pragma unroll
  for (int k = 0; k < 8; k++) acc[k] = 0.f;
  const f16* base = p3 + (size_t)n * 50176 + oct * 8;
  for (int px = strip; px < 784; px += 32) {
    f16x8 v = *(const f16x8*)(base + (size_t)px * 64);
#pragma unroll
    for (int k = 0; k < 8; k++)
      acc[k] += fmaxf((float)v[k] * sc[k] + sh[k], 0.f);
  }
#pragma unroll
  for (int k = 0; k < 8; k++) red[(oct * 8 + k) * 33 + strip] = acc[k];
  __syncthreads();
  if (t < 64) {
    float s = 0.f;
    for (int j = 0; j < 32; j++) s += red[t * 33 + j];
    meanc[t] = s * (1.f / 784.f);
  }
  __syncthreads();
  if (t < 5) {
    float a = fc1b[t];
    for (int i = 0; i < 64; i++) a += meanc[i] * fc1w[i * 5 + t];
    featg[n * 8 + t] = a;
  }
}

// ---------------------------------------------------------------------------
// Quantum gates in registers. Wire w <-> bit (4-w). (verified rounds 1-7)
// ---------------------------------------------------------------------------
template <int W>
DEV void g_rx(float (&sr)[32], float (&si)[32], float c, float s) {
  constexpr int m = 1 << (4 - W);
#pragma unroll
  for (int i0 = 0; i0 < 32; i0++)
    if (!(i0 & m)) {
      int i1 = i0 | m;
      float a0r = sr[i0], a0i = si[i0], a1r = sr[i1], a1i = si[i1];
      sr[i0] = c * a0r + s * a1i;
      si[i0] = c * a0i - s * a1r;
      sr[i1] = s * a0i + c * a1r;
      si[i1] = -s * a0r + c * a1i;
    }
}

template <int W>
DEV void g_ry(float (&sr)[32], float (&si)[32], float c, float s) {
  constexpr int m = 1 << (4 - W);
#pragma unroll
  for (int i0 = 0; i0 < 32; i0++)
    if (!(i0 & m)) {
      int i1 = i0 | m;
      float a0r = sr[i0], a0i = si[i0], a1r = sr[i1], a1i = si[i1];
      sr[i0] = c * a0r - s * a1r;
      si[i0] = c * a0i - s * a1i;
      sr[i1] = s * a0r + c * a1r;
      si[i1] = s * a0i + c * a1i;
    }
}

template <int W>
DEV void g_rz(float (&sr)[32], float (&si)[32], float c, float s) {
  constexpr int m = 1 << (4 - W);
#pragma unroll
  for (int i0 = 0; i0 < 32; i0++)
    if (!(i0 & m)) {
      int i1 = i0 | m;
      float a0r = sr[i0], a0i = si[i0], a1r = sr[i1], a1i = si[i1];
      sr[i0] = c * a0r + s * a0i;
      si[i0] = c * a0i - s * a0r;
      sr[i1] = c * a1r - s * a1i;
      si[i1] = c * a1i + s * a1r;
    }
}

template <int C, int T>
DEV void g_cnot(float (&sr)[32], float (&si)[32]) {
  constexpr int mc = 1 << (4 - C), mt = 1 << (4 - T);
#pragma unroll
  for (int i0 = 0; i0 < 32; i0++)
    if ((i0 & mc) && !(i0 & mt)) {
      int i1 = i0 | mt;
      float tr = sr[i0]; sr[i0] = sr[i1]; sr[i1] = tr;
      float ti = si[i0]; si[i0] = si[i1]; si[i1] = ti;
    }
}

// ---------------------------------------------------------------------------
// head_q: one thread per sample. LN -> quantum -> fc2 -> relu -> fc3 ->
// log_softmax.
// ---------------------------------------------------------------------------
__global__ __launch_bounds__(64) void head_q(
    const float* __restrict__ featg, const float* __restrict__ lng,
    const float* __restrict__ lnb, const float* __restrict__ qp,
    const float* __restrict__ fc2w, const float* __restrict__ fc2b,
    const float* __restrict__ fc3w, const float* __restrict__ fc3b,
    float* __restrict__ out) {
  int n = blockIdx.x * 64 + threadIdx.x;
  float f[5];
#pragma unroll
  for (int i = 0; i < 5; i++) f[i] = featg[n * 8 + i];
  float mu = (f[0] + f[1] + f[2] + f[3] + f[4]) * 0.2f;
  float var = 0.f;
#pragma unroll
  for (int i = 0; i < 5; i++) { float d = f[i] - mu; var += d * d; }
  var *= 0.2f;
  float inv = rsqrtf(var + 1e-5f);
#pragma unroll
  for (int i = 0; i < 5; i++) f[i] = lng[i] * (f[i] - mu) * inv + lnb[i];

  float cx[5], sx[5];
#pragma unroll
  for (int i = 0; i < 5; i++) {
    cx[i] = cosf(0.5f * f[i]);
    sx[i] = sinf(0.5f * f[i]);
  }
  float sr[32], si[32];
#pragma unroll
  for (int i = 0; i < 32; i++) { sr[i] = 0.f; si[i] = 0.f; }
  sr[0] = 1.f;

  for (int l = 0; l < 3; l++) {
    g_rx<0>(sr, si, cx[0], sx[0]);
    g_rx<1>(sr, si, cx[1], sx[1]);
    g_rx<2>(sr, si, cx[2], sx[2]);
    g_rx<3>(sr, si, cx[3], sx[3]);
    g_rx<4>(sr, si, cx[4], sx[4]);
#define WIRE_YZ(I)                                             \
  {                                                            \
    float ty = qp[l * 10 + I];                                 \
    g_ry<I>(sr, si, cosf(0.5f * ty), sinf(0.5f * ty));         \
    float tz = qp[l * 10 + I + 5];                             \
    g_rz<I>(sr, si, cosf(0.5f * tz), sinf(0.5f * tz));         \
  }
    WIRE_YZ(0) WIRE_YZ(1) WIRE_YZ(2) WIRE_YZ(3) WIRE_YZ(4)
#undef WIRE_YZ
    g_cnot<0, 1>(sr, si);
    g_cnot<1, 2>(sr, si);
    g_cnot<2, 3>(sr, si);
    g_cnot<3, 4>(sr, si);
    g_cnot<4, 0>(sr, si);
  }
  float qv = 0.f;
#pragma unroll
  for (int idx = 0; idx < 32; idx++) {
    float p = sr[idx] * sr[idx] + si[idx] * si[idx];
    qv += (__popc(idx & 0x1C) & 1) ? -p : p;
  }
  float l0 = fc3b[0], l1 = fc3b[1];
  for (int j = 0; j < 32; j++) {
    float hv = fmaxf(qv * fc2w[j] + fc2b[j], 0.f);
    l0 += hv * fc3w[j * 2];
    l1 += hv * fc3w[j * 2 + 1];
  }
  float mx = fmaxf(l0, l1);
  float lse = mx + logf(expf(l0 - mx) + expf(l1 - mx));
  out[n * 2 + 0] = l0 - lse;
  out[n * 2 + 1] = l1 - lse;
}

// ---------------------------------------------------------------------------
extern "C" void kernel_launch(void* const* d_in, const int* in_sizes, int n_in,
                              void* d_out, int out_size, void* d_ws,
                              size_t ws_size, hipStream_t stream) {
  const float* x    = (const float*)d_in[0];
  const float* w1   = (const float*)d_in[1];
  const float* bn1g = (const float*)d_in[3];
  const float* bn1b = (const float*)d_in[4];
  const float* w2   = (const float*)d_in[5];
  const float* bn2g = (const float*)d_in[7];
  const float* bn2b = (const float*)d_in[8];
  const float* w3   = (const float*)d_in[9];
  const float* bn3g = (const float*)d_in[11];
  const float* bn3b = (const float*)d_in[12];
  const float* fc1w = (const float*)d_in[13];
  const float* fc1b = (const float*)d_in[14];
  const float* lng  = (const float*)d_in[15];
  const float* lnb  = (const float*)d_in[16];
  const float* qp   = (const float*)d_in[17];
  const float* fc2w = (const float*)d_in[18];
  const float* fc2b = (const float*)d_in[19];
  const float* fc3w = (const float*)d_in[20];
  const float* fc3b = (const float*)d_in[21];
  float* out = (float*)d_out;

  char* ws = (char*)d_ws;
  float* banks1 = (float*)ws;                 // [64][2][16]  8192 B
  float* banks2 = (float*)(ws + 8192);        // [64][2][32] 16384 B (reused as featg)
  float* banks3 = (float*)(ws + 24576);       // [64][2][64] 32768 B
  float* scsh1 = (float*)(ws + 57344);        // [2][16]
  float* scsh2 = (float*)(ws + 57472);        // [2][32]
  float* scsh3 = (float*)(ws + 57728);        // [2][64]
  f16* Bt2 = (f16*)(ws + 58240);              // 32*168 f16 = 10752 B
  f16* Bt3 = (f16*)(ws + 68992);              // 64*296 f16 = 37888 B
  f16* h1 = (f16*)(ws + 106880);              // 51,380,224 el (raw pooled)
  f16* p2 = (f16*)(ws + 106880 + 102760448ULL);
  f16* p3 = (f16*)(ws + 106880 + 102760448ULL + 51380224ULL);
  float* featg = banks2;                      // free by head time

  hipMemsetAsync(ws, 0, 57344, stream);
  repack<<<16, 256, 0, stream>>>(w2, w3, Bt2, Bt3);
  l1_mfma32<<<3584, 256, 0, stream>>>(x, w1, banks1, h1);
  finalize<<<16, 64, 0, stream>>>(banks1, bn1g, bn1b, scsh1, 16,
                                  1.f / 12845056.f);
  l2_gemm<<<3584, 256, 54048, stream>>>(h1, Bt2, scsh1, p2, banks2);
  finalize<<<32, 64, 0, stream>>>(banks2, bn2g, bn2b, scsh2, 32,
                                  1.f / 3211264.f);
  l3_gemm<<<1792, 256, 46912, stream>>>(p2, Bt3, scsh2, p3, banks3);
  finalize<<<64, 64, 0, stream>>>(banks3, bn3g, bn3b, scsh3, 64,
                                  1.f / 802816.f);
  head_pool<<<256, 256, 0, stream>>>(p3, scsh3, fc1w, fc1b, featg);
  head_q<<<4, 64, 0, stream>>>(featg, lng, lnb, qp, fc2w, fc2b, fc3w, fc3b,
                               out);
}

// Round 10
// 341.484 us; speedup vs baseline: 1.0435x; 1.0369x over previous
//
#include <hip/hip_runtime.h>
#include <hip/hip_bf16.h>

// ============================================================================
// HybridModel round 18: l2 register-occupancy fix (1 row/wave, acc halved).
//  - r17 insight: VGPR_Count=104 EXCLUDES accumulators; gfx950's unified
//    VGPR/AGPR file means l2 = ~104+112 = 216 regs/wave -> hard 2 waves/SIMD
//    (= the stuck 20% occupancy). LDS was never the binding resource.
//  - l2 now: block = 4-row superband (grid 7168), wave owns 1 row x 112 pos
//    x 32 oc -> acc[7][2] = 56 AGPR; total ~155 regs <= 170 -> 3 waves/SIMD.
//  - 2x2 pool via lpool across wave pairs (r12 pattern). LDS 39712 B.
//    launch_bounds(256,3) — natural allocation fits, no forced spill.
//  - l1 / l3 (r14) / heads unchanged (attribution).
// ============================================================================

typedef _Float16 f16;
typedef _Float16 f16x2 __attribute__((ext_vector_type(2)));
typedef _Float16 f16x4 __attribute__((ext_vector_type(4)));
typedef _Float16 f16x8 __attribute__((ext_vector_type(8)));
typedef float f32x4 __attribute__((ext_vector_type(4)));
typedef float f32x16 __attribute__((ext_vector_type(16)));

#define DEV static __device__ __forceinline__

DEV float wave_sum(float v) {
#pragma unroll
  for (int off = 32; off > 0; off >>= 1) v += __shfl_xor(v, off, 64);
  return v;
}

// ---------------------------------------------------------------------------
// Weight repack: Bt2[32][168] (k = tap*16+ic, pad 144..167 = 0),
//                Bt3[64][296] (k = tap*32+ic, pad 288..295 = 0), f16.
// ---------------------------------------------------------------------------
__global__ __launch_bounds__(256) void repack(const float* __restrict__ w2,
                                              const float* __restrict__ w3,
                                              f16* __restrict__ Bt2,
                                              f16* __restrict__ Bt3) {
  int t = blockIdx.x * 256 + threadIdx.x;
  int T = gridDim.x * 256;
  for (int i = t; i < 32 * 168; i += T) {
    int oc = i / 168, kk = i - oc * 168;
    float v = 0.f;
    if (kk < 144) {
      int tap = kk >> 4, ic = kk & 15;
      v = w2[(oc * 16 + ic) * 9 + tap];
    }
    Bt2[i] = (f16)v;
  }
  for (int i = t; i < 64 * 296; i += T) {
    int oc = i / 296, kk = i - oc * 296;
    float v = 0.f;
    if (kk < 288) {
      int tap = kk / 32, ic = kk & 31;
      v = w3[(oc * 32 + ic) * 9 + tap];
    }
    Bt3[i] = (f16)v;
  }
}

// ---------------------------------------------------------------------------
// Finalize: banks[64][2][C] -> scsh[2][C]  (scale, shift). 64 thr = 1 wave.
// ---------------------------------------------------------------------------
__global__ __launch_bounds__(64) void finalize(const float* __restrict__ banks,
                                               const float* __restrict__ g,
                                               const float* __restrict__ b,
                                               float* __restrict__ scsh, int C,
                                               float inv_n) {
  int c = blockIdx.x, bk = threadIdx.x;
  float s = banks[bk * 2 * C + c];
  float qq = banks[bk * 2 * C + C + c];
  s = wave_sum(s);
  qq = wave_sum(qq);
  if (bk == 0) {
    float mean = s * inv_n;
    float var = qq * inv_n - mean * mean;
    float sc = g[c] * rsqrtf(var + 1e-5f);
    scsh[c] = sc;
    scsh[C + c] = b[c] - mean * sc;
  }
}

// ---------------------------------------------------------------------------
// L1 via 32x32x16 MFMA (dual-output-row). Unchanged from round 6.
// ---------------------------------------------------------------------------
__global__ __launch_bounds__(256) void l1_mfma32(const float* __restrict__ x,
                                                 const float* __restrict__ w1,
                                                 float* __restrict__ banks,
                                                 f16* __restrict__ h1raw) {
  __shared__ f16 xA[18 * 240];
  __shared__ f16 xB[18 * 240];
  __shared__ f16 lrow[4 * 3616];  // per wave: [2 s][1808]
  __shared__ float lstat[32];
  int bid = blockIdx.x;
  int n = bid / 14, band = bid - n * 14;
  int y0 = band * 16;
  int t = threadIdx.x;
  if (t < 32) lstat[t] = 0.f;
  for (int i = t; i < 1008; i += 256) {
    int r = i / 56, k = i - r * 56;
    int y = y0 - 1 + r;
    float4 v = make_float4(0.f, 0.f, 0.f, 0.f);
    if ((unsigned)y < 224u)
      v = *(const float4*)(x + ((size_t)(n * 224 + y)) * 224 + k * 4);
    f16 h0 = (f16)v.x, h1 = (f16)v.y, h2 = (f16)v.z, h3 = (f16)v.w;
    f16* pa = xA + r * 240 + 4 * k + 1;
    pa[0] = h0; pa[1] = h1; pa[2] = h2; pa[3] = h3;
    f16x4 pk = {h0, h1, h2, h3};
    *(f16x4*)(xB + r * 240 + 4 * k) = pk;
  }
  if (t < 18) {
    xA[t * 240 + 0] = (f16)0.f;
    xA[t * 240 + 225] = (f16)0.f;
    xA[t * 240 + 226] = (f16)0.f;
    xB[t * 240 + 224] = (f16)0.f;
    xB[t * 240 + 225] = (f16)0.f;
  }
  __syncthreads();

  int wave = t >> 6, lane = t & 63;
  int g = lane >> 5, m32 = lane & 31;
  int oc = m32 & 15, s = m32 >> 4;

  f16x8 b;
#pragma unroll
  for (int j = 0; j < 8; j++) {
    int ky = 2 * g + (j >> 2), kx = j & 3;
    int kys = ky - s;
    float wv = 0.f;
    if (kx < 3 && kys >= 0 && kys < 3) wv = w1[oc * 9 + kys * 3 + kx];
    b[j] = (f16)wv;
  }

  const f16* abase = (m32 & 1) ? (xB + (m32 - 1)) : (xA + m32);
  f16* myrow = lrow + wave * 3616;
  f16* mrow = myrow + s * 1808;
  f32x16 zero16;
#pragma unroll
  for (int r = 0; r < 16; r++) zero16[r] = 0.f;
  const int bp[8] = {0, 1, 4, 5, 8, 9, 12, 13};
  float ssum = 0.f, ssq = 0.f;

  for (int rp = wave; rp < 8; rp += 4) {
    int r0 = 2 * rp + 2 * g;
    const f16* rbase = abase + r0 * 240;
#pragma unroll
    for (int xt = 0; xt < 7; xt++) {
      const f16* p0 = rbase + xt * 32;
      f16x2 v0 = *(const f16x2*)(p0);
      f16x2 v1 = *(const f16x2*)(p0 + 2);
      f16x2 v2 = *(const f16x2*)(p0 + 240);
      f16x2 v3 = *(const f16x2*)(p0 + 242);
      f16x8 a = {v0[0], v0[1], v1[0], v1[1], v2[0], v2[1], v3[0], v3[1]};
      f32x16 acc = __builtin_amdgcn_mfma_f32_32x32x16_f16(a, b, zero16, 0, 0, 0);
#pragma unroll
      for (int r = 0; r < 16; r++) {
        float v = acc[r];
        ssum += v;
        ssq += v * v;
      }
#pragma unroll
      for (int i = 0; i < 8; i++) {
        float pm = fmaxf(acc[2 * i], acc[2 * i + 1]);
        int pxp = xt * 16 + bp[i] + 2 * g;
        mrow[pxp * 16 + oc] = (f16)pm;
      }
    }
    int ph = band * 8 + rp;
    f16* gdst = h1raw + ((size_t)(n * 112) + ph) * 112 * 16;
    for (int i = lane; i < 224; i += 64) {
      f16x8 va = *(const f16x8*)(myrow + i * 8);
      f16x8 vb = *(const f16x8*)(myrow + 1808 + i * 8);
#pragma unroll
      for (int k = 0; k < 8; k++) va[k] = (va[k] > vb[k]) ? va[k] : vb[k];
      *(f16x8*)(gdst + i * 8) = va;
    }
  }
  ssum += __shfl_xor(ssum, 16, 64);
  ssum += __shfl_xor(ssum, 32, 64);
  ssq += __shfl_xor(ssq, 16, 64);
  ssq += __shfl_xor(ssq, 32, 64);
  if (lane < 16) {
    atomicAdd(&lstat[oc], ssum);
    atomicAdd(&lstat[16 + oc], ssq);
  }
  __syncthreads();
  if (t < 32) atomicAdd(&banks[(bid & 63) * 32 + t], lstat[t]);
}

// ---------------------------------------------------------------------------
// L2 GEMM round 18: block = 4-row superband, wave = 1 row x 112 pos x 32 oc.
// acc[7][2] = 56 AGPR/wave -> total regs ~155 <= 170 -> 3 waves/SIMD.
// LDS: lin [6][112]x24 = 32256 + zslot 32 + lstat 256 + lpool 7168 = 39712 B.
// 2x2 pool: odd waves publish col-maxes to lpool; even waves combine+store.
// ---------------------------------------------------------------------------
__global__ __launch_bounds__(256, 3) void l2_gemm(
    const f16* __restrict__ h1, const f16* __restrict__ Btg,
    const float* __restrict__ scsh1, f16* __restrict__ p2,
    float* __restrict__ banks) {
  extern __shared__ char smem[];
  f16* lin = (f16*)smem;                  // [6][112] pos x 24 f16 = 32256 B
  f16* zslot = (f16*)(smem + 32256);      // 32 B (16 used)
  float* lstat = (float*)(smem + 32288);  // [4][16] = 256 B
  f16* lpool = (f16*)(smem + 32544);      // [2][56][32] f16 = 7168 B
  int bid = blockIdx.x;
  int n = bid / 28, sb = bid - n * 28;  // img rows sb*4 .. sb*4+3
  int t = threadIdx.x;
  int wave = t >> 6, lane = t & 63, q = lane >> 4, wi = lane & 15;
  const int icq = (q & 1) * 8;

  // B fragments (Bt2 = 10.75 KB, L2-resident).
  f16x8 breg0[5], breg1[5];
#pragma unroll
  for (int j = 0; j < 5; j++) {
    breg0[j] = *(const f16x8*)(Btg + wi * 168 + j * 32 + q * 8);
    breg1[j] = *(const f16x8*)(Btg + (16 + wi) * 168 + j * 32 + q * 8);
  }

  if (t < 64) lstat[t] = 0.f;
  if (t == 0) {
    f16x8 z = {0, 0, 0, 0, 0, 0, 0, 0};
    *(f16x8*)zslot = z;
  }
  // Stage 6 rows (row halo incl), BN1+relu, into lin. 6*224 = 1344 items.
#pragma unroll
  for (int k = 0; k < 6; k++) {
    int i = t + k * 256;
    if (i < 1344) {
      int r = i / 224, c = i - r * 224;  // c: f16x8 unit (pos c>>1, half c&1)
      int y = sb * 4 + r - 1;
      f16x8 o = {0, 0, 0, 0, 0, 0, 0, 0};
      if ((unsigned)y < 112u) {
        f16x8 xv =
            *(const f16x8*)(h1 + ((size_t)(n * 112 + y)) * 112 * 16 + c * 8);
        int ch0 = (c & 1) * 8;
#pragma unroll
        for (int e = 0; e < 8; e++) {
          float f = (float)xv[e] * scsh1[ch0 + e] + scsh1[16 + ch0 + e];
          o[e] = (f16)fmaxf(f, 0.f);
        }
      }
      *(f16x8*)(lin + (r * 112 + (c >> 1)) * 24 + (c & 1) * 8) = o;
    }
  }
  __syncthreads();

  // MFMA: wave owns output row ro = wave (lin row = ro + ky, 0..5).
  f32x4 acc[7][2];
#pragma unroll
  for (int f = 0; f < 7; f++)
#pragma unroll
    for (int nf = 0; nf < 2; nf++)
#pragma unroll
      for (int r = 0; r < 4; r++) acc[f][nf][r] = 0.f;

#pragma unroll
  for (int j = 0; j < 5; j++) {
    const int tA = 2 * j, tB = 2 * j + 1;
    const int kyA = tA / 3, kxA = tA % 3;
    const int kyB = (tB < 9) ? tB / 3 : 0, kxB = (tB < 9) ? tB % 3 : 0;
    bool hiq = (q >= 2);
    int ky = hiq ? kyB : kyA;
    int kx = hiq ? kxB : kxA;
    f16x8 b0 = breg0[j];
    f16x8 b1 = breg1[j];
    int c0 = wi + kx - 1;  // image col for f=0; range [-1, 16]
    const f16* rowbase = lin + (wave + ky) * 112 * 24 + icq;
    // j==4, hiq: B fragment is Bt2's zero pad (cols 144..159) -> exact 0.
#pragma unroll
    for (int f = 0; f < 7; f++) {
      int col = c0 + f * 16;
      // Only f=0 (col=-1) and f=6 (col=112) can be out of range.
      const f16* ap =
          ((unsigned)col < 112u) ? (rowbase + col * 24) : (const f16*)zslot;
      f16x8 a = *(const f16x8*)ap;
      acc[f][0] =
          __builtin_amdgcn_mfma_f32_16x16x32_f16(a, b0, acc[f][0], 0, 0, 0);
      acc[f][1] =
          __builtin_amdgcn_mfma_f32_16x16x32_f16(a, b1, acc[f][1], 0, 0, 0);
    }
  }

  // Stats (raw conv, pre-pool).
  float tS0 = 0.f, tQ0 = 0.f, tS1 = 0.f, tQ1 = 0.f;
#pragma unroll
  for (int f = 0; f < 7; f++)
#pragma unroll
    for (int r = 0; r < 4; r++) {
      float v0 = acc[f][0][r], v1 = acc[f][1][r];
      tS0 += v0; tQ0 += v0 * v0;
      tS1 += v1; tQ1 += v1 * v1;
    }
  tS0 += __shfl_xor(tS0, 16, 64); tS0 += __shfl_xor(tS0, 32, 64);
  tQ0 += __shfl_xor(tQ0, 16, 64); tQ0 += __shfl_xor(tQ0, 32, 64);
  tS1 += __shfl_xor(tS1, 16, 64); tS1 += __shfl_xor(tS1, 32, 64);
  tQ1 += __shfl_xor(tQ1, 16, 64); tQ1 += __shfl_xor(tQ1, 32, 64);
  if (q == 0) {
    atomicAdd(&lstat[wi], tS0);
    atomicAdd(&lstat[16 + wi], tS1);
    atomicAdd(&lstat[32 + wi], tQ0);
    atomicAdd(&lstat[48 + wi], tQ1);
  }

  // Col-pair maxes; odd waves publish to lpool.
  if (wave & 1) {
#pragma unroll
    for (int f = 0; f < 7; f++)
#pragma unroll
      for (int nf = 0; nf < 2; nf++) {
        int ch = nf * 16 + wi;
        int pc0 = f * 8 + q * 2;
        float m0 = fmaxf(acc[f][nf][0], acc[f][nf][1]);
        float m1 = fmaxf(acc[f][nf][2], acc[f][nf][3]);
        lpool[((wave >> 1) * 56 + pc0) * 32 + ch] = (f16)m0;
        lpool[((wave >> 1) * 56 + pc0 + 1) * 32 + ch] = (f16)m1;
      }
  }
  __syncthreads();  // lpool visible; all lstat atomics done

  // Even waves combine row pairs and store p2.
  if (!(wave & 1)) {
    int ph = sb * 2 + (wave >> 1);
    size_t ob = (((size_t)n * 56 + ph) * 56) * 32;
#pragma unroll
    for (int f = 0; f < 7; f++)
#pragma unroll
      for (int nf = 0; nf < 2; nf++) {
        int ch = nf * 16 + wi;
        int pc0 = f * 8 + q * 2;
        float m0 = fmaxf(acc[f][nf][0], acc[f][nf][1]);
        float m1 = fmaxf(acc[f][nf][2], acc[f][nf][3]);
        m0 = fmaxf(m0, (float)lpool[((wave >> 1) * 56 + pc0) * 32 + ch]);
        m1 = fmaxf(m1, (float)lpool[((wave >> 1) * 56 + pc0 + 1) * 32 + ch]);
        p2[ob + (size_t)pc0 * 32 + ch] = (f16)m0;
        p2[ob + (size_t)(pc0 + 1) * 32 + ch] = (f16)m1;
      }
  }

  if (t < 64) {
    int i = t >> 5, c = t & 31;
    atomicAdd(&banks[(bid & 63) * 64 + i * 32 + c], lstat[i * 32 + c]);
  }
}

// ---------------------------------------------------------------------------
// L3 GEMM (r14, validated): one block = (n, 8-row superband). Each wave
// computes 112 positions x ALL 64 oc (4 B-frags per A-read).
// LDS: lin [10][58]x40 f16 = 46400 + lstat 512 = 46912 B; lpool aliases lin.
// ---------------------------------------------------------------------------
__global__ __launch_bounds__(256, 2) void l3_gemm(
    const f16* __restrict__ p2, const f16* __restrict__ Btg,
    const float* __restrict__ scsh2, f16* __restrict__ p3,
    float* __restrict__ banks) {
  extern __shared__ char smem[];
  f16* lin = (f16*)smem;                  // [10][58] pos x 40 f16 = 46400 B
  float* lstat = (float*)(smem + 46400);  // [2][64] = 512 B
  f16* lpool = (f16*)smem;                // aliases lin post-MFMA (28672 B)
  int bx = blockIdx.x;
  int n = bx / 7, sb = bx - n * 7;  // img rows sb*8 .. sb*8+7
  int t = threadIdx.x;
  int wave = t >> 6, lane = t & 63, q = lane >> 4, wi = lane & 15;

  // B fragments: all 64 oc per wave (36 x f16x8; Bt3 is L2-resident).
  f16x8 breg[9][4];
#pragma unroll
  for (int j = 0; j < 9; j++)
#pragma unroll
    for (int h = 0; h < 4; h++)
      breg[j][h] =
          *(const f16x8*)(Btg + (h * 16 + wi) * 296 + j * 32 + q * 8);

  if (t < 128) lstat[t] = 0.f;
  // Stage 10 rows (halo included), BN2+relu, into lin.
#pragma unroll
  for (int k = 0; k < 9; k++) {
    int i = t + k * 256;
    if (i < 2240) {
      int r = i / 224, rem = i - r * 224;
      int c = rem >> 2, cp = rem & 3;
      int y = sb * 8 + r - 1;
      f16x8 o = {0, 0, 0, 0, 0, 0, 0, 0};
      if ((unsigned)y < 56u) {
        f16x8 xv =
            *(const f16x8*)(p2 + (((size_t)(n * 56 + y)) * 56 + c) * 32 +
                            cp * 8);
        int ch0 = cp * 8;
#pragma unroll
        for (int e = 0; e < 8; e++) {
          float f = (float)xv[e] * scsh2[ch0 + e] + scsh2[32 + ch0 + e];
          o[e] = (f16)fmaxf(f, 0.f);
        }
      }
      *(f16x8*)(lin + (r * 58 + 1 + c) * 40 + cp * 8) = o;
    }
  }
  // Zero halo columns (pos 0 and 57), rows 0..9.
  if (t < 80) {
    int r = t / 8, k = t & 7;
    int col = (k < 4) ? 0 : 57, cp = k & 3;
    f16x8 z = {0, 0, 0, 0, 0, 0, 0, 0};
    *(f16x8*)(lin + (r * 58 + col) * 40 + cp * 8) = z;
  }
  __syncthreads();

  int abase[7];
#pragma unroll
  for (int f = 0; f < 7; f++) {
    int pos = wave * 112 + f * 16 + wi;
    int r = pos / 56, w = pos - r * 56;
    abase[f] = (r * 58 + w) * 40 + q * 8;
  }
  f32x4 acc[7][4];
#pragma unroll
  for (int f = 0; f < 7; f++)
#pragma unroll
    for (int h = 0; h < 4; h++)
#pragma unroll
      for (int r = 0; r < 4; r++) acc[f][h][r] = 0.f;

#pragma unroll
  for (int j = 0; j < 9; j++) {
    const int ky = j / 3, kx = j % 3;
#pragma unroll
    for (int f = 0; f < 7; f++) {
      f16x8 a = *(const f16x8*)(lin + abase[f] + (ky * 58 + kx) * 40);
#pragma unroll
      for (int h = 0; h < 4; h++)
        acc[f][h] =
            __builtin_amdgcn_mfma_f32_16x16x32_f16(a, breg[j][h], acc[f][h],
                                                   0, 0, 0);
    }
  }

  // Stats: channel = h*16 + wi; reduce across q via shfl, atomic to lstat.
  float tS[4] = {0.f, 0.f, 0.f, 0.f}, tQ[4] = {0.f, 0.f, 0.f, 0.f};
#pragma unroll
  for (int f = 0; f < 7; f++)
#pragma unroll
    for (int h = 0; h < 4; h++)
#pragma unroll
      for (int r = 0; r < 4; r++) {
        float v = acc[f][h][r];
        tS[h] += v;
        tQ[h] += v * v;
      }
#pragma unroll
  for (int h = 0; h < 4; h++) {
    tS[h] += __shfl_xor(tS[h], 16, 64); tS[h] += __shfl_xor(tS[h], 32, 64);
    tQ[h] += __shfl_xor(tQ[h], 16, 64); tQ[h] += __shfl_xor(tQ[h], 32, 64);
  }
  if (q == 0) {
#pragma unroll
    for (int h = 0; h < 4; h++) {
      atomicAdd(&lstat[h * 16 + wi], tS[h]);
      atomicAdd(&lstat[64 + h * 16 + wi], tQ[h]);
    }
  }
  __syncthreads();  // all lin reads done; lpool may now alias lin

  // Col-pair maxes -> lpool[8][28][64].
#pragma unroll
  for (int f = 0; f < 7; f++) {
    int pos = wave * 112 + f * 16 + q * 4;  // multiple of 4
    int r0 = pos / 56, w0 = pos - r0 * 56;
#pragma unroll
    for (int h = 0; h < 4; h++) {
      int ch = h * 16 + wi;
      float m0 = fmaxf(acc[f][h][0], acc[f][h][1]);
      float m1 = fmaxf(acc[f][h][2], acc[f][h][3]);
      lpool[(r0 * 28 + (w0 >> 1)) * 64 + ch] = (f16)m0;
      lpool[(r0 * 28 + (w0 >> 1) + 1) * 64 + ch] = (f16)m1;
    }
  }
  __syncthreads();

  // Row-pair combine + p3 store (4 pooled rows x 28 x 64 = 7168).
  for (int i = t; i < 7168; i += 256) {
    int ch = i & 63, rest = i >> 6;
    int pc = rest % 28, pr = rest / 28;  // pr 0..3
    float v = fmaxf((float)lpool[((2 * pr) * 28 + pc) * 64 + ch],
                    (float)lpool[((2 * pr + 1) * 28 + pc) * 64 + ch]);
    int gpr = sb * 4 + pr;
    p3[(((size_t)n * 28 + gpr) * 28 + pc) * 64 + ch] = (f16)v;
  }
  if (t < 128) {
    atomicAdd(&banks[(bx & 63) * 128 + t], lstat[t]);
  }
}

// ---------------------------------------------------------------------------
// head_pool: BN3+relu+avgpool(p3) coalesced + fc1 -> feat[n][8] (first 5).
// ---------------------------------------------------------------------------
__global__ __launch_bounds__(256) void head_pool(
    const f16* __restrict__ p3, const float* __restrict__ scsh3,
    const float* __restrict__ fc1w, const float* __restrict__ fc1b,
    float* __restrict__ featg) {
  int n = blockIdx.x, t = threadIdx.x;
  __shared__ float red[64 * 33];
  __shared__ float meanc[64];
  int oct = t & 7, strip = t >> 3;
  float sc[8], sh[8];
#pragma unroll
  for (int k = 0; k < 8; k++) {
    sc[k] = scsh3[oct * 8 + k];
    sh[k] = scsh3[64 + oct * 8 + k];
  }
  float acc[8];
#pragma unroll
  for (int k = 0; k < 8; k++) acc[k] = 0.f;
  const f16* base = p3 + (size_t)n * 50176 + oct * 8;
  for (int px = strip; px < 784; px += 32) {
    f16x8 v = *(const f16x8*)(base + (size_t)px * 64);
#pragma unroll
    for (int k = 0; k < 8; k++)
      acc[k] += fmaxf((float)v[k] * sc[k] + sh[k], 0.f);
  }
#pragma unroll
  for (int k = 0; k < 8; k++) red[(oct * 8 + k) * 33 + strip] = acc[k];
  __syncthreads();
  if (t < 64) {
    float s = 0.f;
    for (int j = 0; j < 32; j++) s += red[t * 33 + j];
    meanc[t] = s * (1.f / 784.f);
  }
  __syncthreads();
  if (t < 5) {
    float a = fc1b[t];
    for (int i = 0; i < 64; i++) a += meanc[i] * fc1w[i * 5 + t];
    featg[n * 8 + t] = a;
  }
}

// ---------------------------------------------------------------------------
// Quantum gates in registers. Wire w <-> bit (4-w). (verified rounds 1-7)
// ---------------------------------------------------------------------------
template <int W>
DEV void g_rx(float (&sr)[32], float (&si)[32], float c, float s) {
  constexpr int m = 1 << (4 - W);
#pragma unroll
  for (int i0 = 0; i0 < 32; i0++)
    if (!(i0 & m)) {
      int i1 = i0 | m;
      float a0r = sr[i0], a0i = si[i0], a1r = sr[i1], a1i = si[i1];
      sr[i0] = c * a0r + s * a1i;
      si[i0] = c * a0i - s * a1r;
      sr[i1] = s * a0i + c * a1r;
      si[i1] = -s * a0r + c * a1i;
    }
}

template <int W>
DEV void g_ry(float (&sr)[32], float (&si)[32], float c, float s) {
  constexpr int m = 1 << (4 - W);
#pragma unroll
  for (int i0 = 0; i0 < 32; i0++)
    if (!(i0 & m)) {
      int i1 = i0 | m;
      float a0r = sr[i0], a0i = si[i0], a1r = sr[i1], a1i = si[i1];
      sr[i0] = c * a0r - s * a1r;
      si[i0] = c * a0i - s * a1i;
      sr[i1] = s * a0r + c * a1r;
      si[i1] = s * a0i + c * a1i;
    }
}

template <int W>
DEV void g_rz(float (&sr)[32], float (&si)[32], float c, float s) {
  constexpr int m = 1 << (4 - W);
#pragma unroll
  for (int i0 = 0; i0 < 32; i0++)
    if (!(i0 & m)) {
      int i1 = i0 | m;
      float a0r = sr[i0], a0i = si[i0], a1r = sr[i1], a1i = si[i1];
      sr[i0] = c * a0r + s * a0i;
      si[i0] = c * a0i - s * a0r;
      sr[i1] = c * a1r - s * a1i;
      si[i1] = c * a1i + s * a1r;
    }
}

template <int C, int T>
DEV void g_cnot(float (&sr)[32], float (&si)[32]) {
  constexpr int mc = 1 << (4 - C), mt = 1 << (4 - T);
#pragma unroll
  for (int i0 = 0; i0 < 32; i0++)
    if ((i0 & mc) && !(i0 & mt)) {
      int i1 = i0 | mt;
      float tr = sr[i0]; sr[i0] = sr[i1]; sr[i1] = tr;
      float ti = si[i0]; si[i0] = si[i1]; si[i1] = ti;
    }
}

// ---------------------------------------------------------------------------
// head_q: one thread per sample. LN -> quantum -> fc2 -> relu -> fc3 ->
// log_softmax.
// ---------------------------------------------------------------------------
__global__ __launch_bounds__(64) void head_q(
    const float* __restrict__ featg, const float* __restrict__ lng,
    const float* __restrict__ lnb, const float* __restrict__ qp,
    const float* __restrict__ fc2w, const float* __restrict__ fc2b,
    const float* __restrict__ fc3w, const float* __restrict__ fc3b,
    float* __restrict__ out) {
  int n = blockIdx.x * 64 + threadIdx.x;
  float f[5];
#pragma unroll
  for (int i = 0; i < 5; i++) f[i] = featg[n * 8 + i];
  float mu = (f[0] + f[1] + f[2] + f[3] + f[4]) * 0.2f;
  float var = 0.f;
#pragma unroll
  for (int i = 0; i < 5; i++) { float d = f[i] - mu; var += d * d; }
  var *= 0.2f;
  float inv = rsqrtf(var + 1e-5f);
#pragma unroll
  for (int i = 0; i < 5; i++) f[i] = lng[i] * (f[i] - mu) * inv + lnb[i];

  float cx[5], sx[5];
#pragma unroll
  for (int i = 0; i < 5; i++) {
    cx[i] = cosf(0.5f * f[i]);
    sx[i] = sinf(0.5f * f[i]);
  }
  float sr[32], si[32];
#pragma unroll
  for (int i = 0; i < 32; i++) { sr[i] = 0.f; si[i] = 0.f; }
  sr[0] = 1.f;

  for (int l = 0; l < 3; l++) {
    g_rx<0>(sr, si, cx[0], sx[0]);
    g_rx<1>(sr, si, cx[1], sx[1]);
    g_rx<2>(sr, si, cx[2], sx[2]);
    g_rx<3>(sr, si, cx[3], sx[3]);
    g_rx<4>(sr, si, cx[4], sx[4]);
#define WIRE_YZ(I)                                             \
  {                                                            \
    float ty = qp[l * 10 + I];                                 \
    g_ry<I>(sr, si, cosf(0.5f * ty), sinf(0.5f * ty));         \
    float tz = qp[l * 10 + I + 5];                             \
    g_rz<I>(sr, si, cosf(0.5f * tz), sinf(0.5f * tz));         \
  }
    WIRE_YZ(0) WIRE_YZ(1) WIRE_YZ(2) WIRE_YZ(3) WIRE_YZ(4)
#undef WIRE_YZ
    g_cnot<0, 1>(sr, si);
    g_cnot<1, 2>(sr, si);
    g_cnot<2, 3>(sr, si);
    g_cnot<3, 4>(sr, si);
    g_cnot<4, 0>(sr, si);
  }
  float qv = 0.f;
#pragma unroll
  for (int idx = 0; idx < 32; idx++) {
    float p = sr[idx] * sr[idx] + si[idx] * si[idx];
    qv += (__popc(idx & 0x1C) & 1) ? -p : p;
  }
  float l0 = fc3b[0], l1 = fc3b[1];
  for (int j = 0; j < 32; j++) {
    float hv = fmaxf(qv * fc2w[j] + fc2b[j], 0.f);
    l0 += hv * fc3w[j * 2];
    l1 += hv * fc3w[j * 2 + 1];
  }
  float mx = fmaxf(l0, l1);
  float lse = mx + logf(expf(l0 - mx) + expf(l1 - mx));
  out[n * 2 + 0] = l0 - lse;
  out[n * 2 + 1] = l1 - lse;
}

// ---------------------------------------------------------------------------
extern "C" void kernel_launch(void* const* d_in, const int* in_sizes, int n_in,
                              void* d_out, int out_size, void* d_ws,
                              size_t ws_size, hipStream_t stream) {
  const float* x    = (const float*)d_in[0];
  const float* w1   = (const float*)d_in[1];
  const float* bn1g = (const float*)d_in[3];
  const float* bn1b = (const float*)d_in[4];
  const float* w2   = (const float*)d_in[5];
  const float* bn2g = (const float*)d_in[7];
  const float* bn2b = (const float*)d_in[8];
  const float* w3   = (const float*)d_in[9];
  const float* bn3g = (const float*)d_in[11];
  const float* bn3b = (const float*)d_in[12];
  const float* fc1w = (const float*)d_in[13];
  const float* fc1b = (const float*)d_in[14];
  const float* lng  = (const float*)d_in[15];
  const float* lnb  = (const float*)d_in[16];
  const float* qp   = (const float*)d_in[17];
  const float* fc2w = (const float*)d_in[18];
  const float* fc2b = (const float*)d_in[19];
  const float* fc3w = (const float*)d_in[20];
  const float* fc3b = (const float*)d_in[21];
  float* out = (float*)d_out;

  char* ws = (char*)d_ws;
  float* banks1 = (float*)ws;                 // [64][2][16]  8192 B
  float* banks2 = (float*)(ws + 8192);        // [64][2][32] 16384 B (reused as featg)
  float* banks3 = (float*)(ws + 24576);       // [64][2][64] 32768 B
  float* scsh1 = (float*)(ws + 57344);        // [2][16]
  float* scsh2 = (float*)(ws + 57472);        // [2][32]
  float* scsh3 = (float*)(ws + 57728);        // [2][64]
  f16* Bt2 = (f16*)(ws + 58240);              // 32*168 f16 = 10752 B
  f16* Bt3 = (f16*)(ws + 68992);              // 64*296 f16 = 37888 B
  f16* h1 = (f16*)(ws + 106880);              // 51,380,224 el (raw pooled)
  f16* p2 = (f16*)(ws + 106880 + 102760448ULL);
  f16* p3 = (f16*)(ws + 106880 + 102760448ULL + 51380224ULL);
  float* featg = banks2;                      // free by head time

  hipMemsetAsync(ws, 0, 57344, stream);
  repack<<<16, 256, 0, stream>>>(w2, w3, Bt2, Bt3);
  l1_mfma32<<<3584, 256, 0, stream>>>(x, w1, banks1, h1);
  finalize<<<16, 64, 0, stream>>>(banks1, bn1g, bn1b, scsh1, 16,
                                  1.f / 12845056.f);
  l2_gemm<<<7168, 256, 39712, stream>>>(h1, Bt2, scsh1, p2, banks2);
  finalize<<<32, 64, 0, stream>>>(banks2, bn2g, bn2b, scsh2, 32,
                                  1.f / 3211264.f);
  l3_gemm<<<1792, 256, 46912, stream>>>(p2, Bt3, scsh2, p3, banks3);
  finalize<<<64, 64, 0, stream>>>(banks3, bn3g, bn3b, scsh3, 64,
                                  1.f / 802816.f);
  head_pool<<<256, 256, 0, stream>>>(p3, scsh3, fc1w, fc1b, featg);
  head_q<<<4, 64, 0, stream>>>(featg, lng, lnb, qp, fc2w, fc2b, fc3w, fc3b,
                               out);
}